// Round 1
// baseline (1720.740 us; speedup 1.0000x reference)
//
#include <hip/hip_runtime.h>

#define NN 50000
#define NE 800000
#define HD 128
#define NL 4
#define NC 10
#define NG 256

__device__ __forceinline__ float sigmf(float x){ return 1.0f/(1.0f + __expf(-x)); }
__device__ __forceinline__ float tanhff(float x){ return 2.0f/(1.0f + __expf(-2.0f*x)) - 1.0f; }

__device__ __forceinline__ void fma4(float4& acc, float s, const float4 b){
  acc.x = fmaf(s, b.x, acc.x);
  acc.y = fmaf(s, b.y, acc.y);
  acc.z = fmaf(s, b.z, acc.z);
  acc.w = fmaf(s, b.w, acc.w);
}

// ---------------- prep: transpose weights to [k][n] layouts ----------------
// wT_ih[k*384+n] = w_ih[n*128+k]; wT_hh same; lwT[k*128+n] = local_w[n*128+k]
__global__ __launch_bounds__(256) void prep_transpose(
    const float* __restrict__ w_ih, const float* __restrict__ w_hh,
    const float* __restrict__ local_w,
    float* __restrict__ wT_ih, float* __restrict__ wT_hh, float* __restrict__ lwT)
{
  int idx = blockIdx.x*256 + threadIdx.x;
  if (idx < 49152){
    int k = idx/384, n = idx - k*384;
    wT_ih[idx] = w_ih[n*128 + k];
  } else if (idx < 98304){
    int j = idx - 49152;
    int k = j/384, n = j - k*384;
    wT_hh[j] = w_hh[n*128 + k];
  } else if (idx < 114688){
    int j = idx - 98304;
    int k = j >> 7, n = j & 127;
    lwT[j] = local_w[n*128 + k];
  }
}

// ---------------- CSR build ----------------
__global__ __launch_bounds__(256) void count_deg(const int* __restrict__ dst, int* deg)
{
  int e = blockIdx.x*256 + threadIdx.x;
  if (e < NE) atomicAdd(&deg[dst[e]], 1);
}

// degcur holds degrees on entry; on exit holds row start offsets (cursor),
// row_ptr holds the same offsets (+ row_ptr[NN] = NE).
__global__ __launch_bounds__(1024) void scan_kernel(int* degcur, int* __restrict__ row_ptr)
{
  __shared__ int sdata[1024];
  __shared__ int carry_s;
  int t = threadIdx.x;
  if (t == 0) carry_s = 0;
  __syncthreads();
  for (int base = 0; base < NN; base += 1024){
    int v = (base + t < NN) ? degcur[base + t] : 0;
    sdata[t] = v;
    __syncthreads();
    for (int off = 1; off < 1024; off <<= 1){
      int x = (t >= off) ? sdata[t - off] : 0;
      __syncthreads();
      sdata[t] += x;
      __syncthreads();
    }
    int excl = sdata[t] - v;
    int c = carry_s;
    if (base + t < NN){
      row_ptr[base + t] = c + excl;
      degcur[base + t]  = c + excl;
    }
    __syncthreads();
    if (t == 0) carry_s = c + sdata[1023];
    __syncthreads();
  }
  if (t == 0) row_ptr[NN] = carry_s;
}

__global__ __launch_bounds__(256) void fill_csr(
    const int* __restrict__ src, const int* __restrict__ dst,
    int* cursor, int* __restrict__ csr_src)
{
  int e = blockIdx.x*256 + threadIdx.x;
  if (e < NE){
    int pos = atomicAdd(&cursor[dst[e]], 1);
    csr_src[pos] = src[e];
  }
}

// ---------------- K1: C[n][f] = sum_k A[n][k] * B[k][f]; B is 128x128 [k][n] ----------------
// block 256 = 16 tx (8 feats each) x 16 ty (4 nodes each); tile 64 nodes x 128 feats
__global__ __launch_bounds__(256) void gemm_nodes(
    const float* __restrict__ A, const float* __restrict__ B, float* __restrict__ Cc)
{
  __shared__ float a_s[64*36];
  __shared__ float b_s[32*128];
  int t = threadIdx.x;
  int tx = t & 15, ty = t >> 4;
  int f0 = tx*8;
  int nb = blockIdx.x * 64;
  float4 acc0[4], acc1[4];
  #pragma unroll
  for (int i=0;i<4;i++){ acc0[i]=make_float4(0,0,0,0); acc1[i]=make_float4(0,0,0,0); }

  for (int kc = 0; kc < 4; kc++){
    #pragma unroll
    for (int q=0;q<2;q++){             // stage A chunk: 64 nodes x 32 k
      int idx4 = t*2 + q;              // 0..511
      int node = idx4 >> 3;
      int kk4 = (idx4 & 7) * 4;
      int ng = nb + node;
      float4 val = make_float4(0,0,0,0);
      if (ng < NN) val = *(const float4*)&A[(size_t)ng*HD + kc*32 + kk4];
      *(float4*)&a_s[node*36 + kk4] = val;
    }
    #pragma unroll
    for (int q=0;q<4;q++){             // stage B chunk: 32 k x 128 f
      int idx4 = q*256 + t;            // 0..1023
      int flat = idx4*4;
      int kk = flat >> 7, f = flat & 127;
      *(float4*)&b_s[kk*128 + f] = *(const float4*)&B[(kc*32+kk)*128 + f];
    }
    __syncthreads();
    #pragma unroll 8
    for (int kk = 0; kk < 32; kk++){
      float a_[4];
      #pragma unroll
      for (int i=0;i<4;i++) a_[i] = a_s[(ty*4+i)*36 + kk];
      float4 b0 = *(float4*)&b_s[kk*128 + f0];
      float4 b1 = *(float4*)&b_s[kk*128 + f0 + 4];
      #pragma unroll
      for (int i=0;i<4;i++){ fma4(acc0[i], a_[i], b0); fma4(acc1[i], a_[i], b1); }
    }
    __syncthreads();
  }
  #pragma unroll
  for (int i=0;i<4;i++){
    int n = nb + ty*4 + i;
    if (n < NN){
      *(float4*)&Cc[(size_t)n*HD + f0]     = acc0[i];
      *(float4*)&Cc[(size_t)n*HD + f0 + 4] = acc1[i];
    }
  }
}

// ---------------- K2: aggr[n] = sum over incoming edges of m[src] ----------------
__global__ __launch_bounds__(256) void aggregate(
    const float* __restrict__ m, const int* __restrict__ row_ptr,
    const int* __restrict__ csr_src, float* __restrict__ aggr)
{
  int nid = blockIdx.x*4 + (threadIdx.x >> 6);
  int lane = threadIdx.x & 63;
  if (nid >= NN) return;
  int s0 = row_ptr[nid], s1 = row_ptr[nid+1];
  float2 acc = make_float2(0.f, 0.f);
  const float2* m2 = (const float2*)m;
  for (int j = s0; j < s1; j++){
    int s = csr_src[j];
    float2 v = m2[(size_t)s*64 + lane];
    acc.x += v.x; acc.y += v.y;
  }
  ((float2*)aggr)[(size_t)nid*64 + lane] = acc;
}

// ---------------- K3: fused GRU cell ----------------
// block 256 = 32 tx (4 feats) x 8 ty (4 nodes); tile 32 nodes x 128 feats
// accumulators: s_r = aggr@wih_r^T + h@whh_r^T ; s_z similarly ; gin = aggr@wih_n^T ; ghn = h@whh_n^T
__global__ __launch_bounds__(256) void gru_fused(
    const float* __restrict__ aggr, const float* h_in,
    const float* __restrict__ wT_ih, const float* __restrict__ wT_hh,
    const float* __restrict__ b_ih, const float* __restrict__ b_hh,
    float* h_out)
{
  __shared__ float a_s[32*20];
  __shared__ float h_s[32*20];
  __shared__ float w_s[6*16*128];   // [mi][kk][f]; mi: 0=ih_r 1=ih_z 2=ih_n 3=hh_r 4=hh_z 5=hh_n
  int t = threadIdx.x;
  int tx = t & 31, ty = t >> 5;
  int f0 = tx*4;
  int nb = blockIdx.x*32;
  float4 sr[4], sz[4], gin[4], ghn[4];
  #pragma unroll
  for (int i=0;i<4;i++){
    sr[i]=make_float4(0,0,0,0); sz[i]=make_float4(0,0,0,0);
    gin[i]=make_float4(0,0,0,0); ghn[i]=make_float4(0,0,0,0);
  }

  for (int kc = 0; kc < 8; kc++){
    {   // stage a (waves 0-1) and h (waves 2-3): 32 nodes x 16 k each
      int idx4 = t & 127;
      int node = idx4 >> 2;
      int kk4 = (idx4 & 3) * 4;
      int ng = nb + node;
      const float* srcp = (t < 128) ? aggr : h_in;
      float* dstp = (t < 128) ? a_s : h_s;
      float4 val = make_float4(0,0,0,0);
      if (ng < NN) val = *(const float4*)&srcp[(size_t)ng*HD + kc*16 + kk4];
      *(float4*)&dstp[node*20 + kk4] = val;
    }
    #pragma unroll
    for (int q=0; q<12; q++){          // stage 6 weight slabs: 6 x 16k x 128f
      int idx4 = q*256 + t;
      int flat = idx4*4;
      int mi = flat >> 11;
      int rem = flat & 2047;
      int kk = rem >> 7;
      int f = rem & 127;
      const float* wsrc = (mi < 3) ? wT_ih : wT_hh;
      int gate = (mi < 3) ? mi : (mi-3);
      *(float4*)&w_s[mi*2048 + kk*128 + f] = *(const float4*)&wsrc[(kc*16+kk)*384 + gate*128 + f];
    }
    __syncthreads();
    #pragma unroll 4
    for (int kk = 0; kk < 16; kk++){
      float a_[4], hh_[4];
      #pragma unroll
      for (int i=0;i<4;i++){
        a_[i]  = a_s[(ty*4+i)*20 + kk];
        hh_[i] = h_s[(ty*4+i)*20 + kk];
      }
      const float4 wir = *(const float4*)&w_s[        kk*128 + f0];
      const float4 wiz = *(const float4*)&w_s[2048 +  kk*128 + f0];
      const float4 win = *(const float4*)&w_s[4096 +  kk*128 + f0];
      const float4 whr = *(const float4*)&w_s[6144 +  kk*128 + f0];
      const float4 whz = *(const float4*)&w_s[8192 +  kk*128 + f0];
      const float4 whn = *(const float4*)&w_s[10240 + kk*128 + f0];
      #pragma unroll
      for (int i=0;i<4;i++){
        fma4(sr[i],  a_[i],  wir); fma4(sr[i],  hh_[i], whr);
        fma4(sz[i],  a_[i],  wiz); fma4(sz[i],  hh_[i], whz);
        fma4(gin[i], a_[i],  win);
        fma4(ghn[i], hh_[i], whn);
      }
    }
    __syncthreads();
  }

  float4 bir = *(const float4*)&b_ih[f0];
  float4 biz = *(const float4*)&b_ih[128 + f0];
  float4 bin = *(const float4*)&b_ih[256 + f0];
  float4 bhr = *(const float4*)&b_hh[f0];
  float4 bhz = *(const float4*)&b_hh[128 + f0];
  float4 bhn = *(const float4*)&b_hh[256 + f0];

  #pragma unroll
  for (int i=0;i<4;i++){
    int n = nb + ty*4 + i;
    if (n >= NN) continue;
    float4 ho = *(const float4*)&h_in[(size_t)n*HD + f0];
    float4 hn;
    {
      float r  = sigmf(sr[i].x + bir.x + bhr.x);
      float zg = sigmf(sz[i].x + biz.x + bhz.x);
      float ng_ = tanhff(gin[i].x + bin.x + r*(ghn[i].x + bhn.x));
      hn.x = (1.0f - zg)*ng_ + zg*ho.x;
    }
    {
      float r  = sigmf(sr[i].y + bir.y + bhr.y);
      float zg = sigmf(sz[i].y + biz.y + bhz.y);
      float ng_ = tanhff(gin[i].y + bin.y + r*(ghn[i].y + bhn.y));
      hn.y = (1.0f - zg)*ng_ + zg*ho.y;
    }
    {
      float r  = sigmf(sr[i].z + bir.z + bhr.z);
      float zg = sigmf(sz[i].z + biz.z + bhz.z);
      float ng_ = tanhff(gin[i].z + bin.z + r*(ghn[i].z + bhn.z));
      hn.z = (1.0f - zg)*ng_ + zg*ho.z;
    }
    {
      float r  = sigmf(sr[i].w + bir.w + bhr.w);
      float zg = sigmf(sz[i].w + biz.w + bhz.w);
      float ng_ = tanhff(gin[i].w + bin.w + r*(ghn[i].w + bhn.w));
      hn.w = (1.0f - zg)*ng_ + zg*ho.w;
    }
    *(float4*)&h_out[(size_t)n*HD + f0] = hn;
  }
}

// ---------------- local head + mean-pool accumulate ----------------
__global__ __launch_bounds__(256) void local_pool(
    const float* __restrict__ A, const float* __restrict__ B,
    const float* __restrict__ bias, const int* __restrict__ batch,
    float* pooled, float* cntf)
{
  __shared__ float a_s[64*36];
  __shared__ float b_s[32*128];
  int t = threadIdx.x;
  int tx = t & 15, ty = t >> 4;
  int f0 = tx*8;
  int nb = blockIdx.x * 64;
  float4 acc0[4], acc1[4];
  #pragma unroll
  for (int i=0;i<4;i++){ acc0[i]=make_float4(0,0,0,0); acc1[i]=make_float4(0,0,0,0); }

  for (int kc = 0; kc < 4; kc++){
    #pragma unroll
    for (int q=0;q<2;q++){
      int idx4 = t*2 + q;
      int node = idx4 >> 3;
      int kk4 = (idx4 & 7) * 4;
      int ng = nb + node;
      float4 val = make_float4(0,0,0,0);
      if (ng < NN) val = *(const float4*)&A[(size_t)ng*HD + kc*32 + kk4];
      *(float4*)&a_s[node*36 + kk4] = val;
    }
    #pragma unroll
    for (int q=0;q<4;q++){
      int idx4 = q*256 + t;
      int flat = idx4*4;
      int kk = flat >> 7, f = flat & 127;
      *(float4*)&b_s[kk*128 + f] = *(const float4*)&B[(kc*32+kk)*128 + f];
    }
    __syncthreads();
    #pragma unroll 8
    for (int kk = 0; kk < 32; kk++){
      float a_[4];
      #pragma unroll
      for (int i=0;i<4;i++) a_[i] = a_s[(ty*4+i)*36 + kk];
      float4 b0 = *(float4*)&b_s[kk*128 + f0];
      float4 b1 = *(float4*)&b_s[kk*128 + f0 + 4];
      #pragma unroll
      for (int i=0;i<4;i++){ fma4(acc0[i], a_[i], b0); fma4(acc1[i], a_[i], b1); }
    }
    __syncthreads();
  }
  float4 bv0 = *(const float4*)&bias[f0];
  float4 bv1 = *(const float4*)&bias[f0 + 4];
  #pragma unroll
  for (int i=0;i<4;i++){
    int n = nb + ty*4 + i;
    if (n >= NN) continue;
    int g = batch[n];
    float* pr = pooled + (size_t)g*HD;
    atomicAdd(&pr[f0+0], fmaxf(acc0[i].x + bv0.x, 0.f));
    atomicAdd(&pr[f0+1], fmaxf(acc0[i].y + bv0.y, 0.f));
    atomicAdd(&pr[f0+2], fmaxf(acc0[i].z + bv0.z, 0.f));
    atomicAdd(&pr[f0+3], fmaxf(acc0[i].w + bv0.w, 0.f));
    atomicAdd(&pr[f0+4], fmaxf(acc1[i].x + bv1.x, 0.f));
    atomicAdd(&pr[f0+5], fmaxf(acc1[i].y + bv1.y, 0.f));
    atomicAdd(&pr[f0+6], fmaxf(acc1[i].z + bv1.z, 0.f));
    atomicAdd(&pr[f0+7], fmaxf(acc1[i].w + bv1.w, 0.f));
    if (tx == 0) atomicAdd(&cntf[g], 1.0f);
  }
}

// ---------------- classifier + log_softmax ----------------
__global__ __launch_bounds__(64) void classifier_kernel(
    const float* __restrict__ pooled, const float* __restrict__ cntf,
    const float* __restrict__ gw, const float* __restrict__ gb,
    float* __restrict__ out)
{
  int g = blockIdx.x;
  int lane = threadIdx.x;
  float cnt = cntf[g];
  if (cnt < 1.0f) cnt = 1.0f;
  float inv = 1.0f / cnt;
  float p0 = pooled[g*HD + lane] * inv;
  float p1 = pooled[g*HD + 64 + lane] * inv;
  float vals[NC];
  #pragma unroll
  for (int c=0;c<NC;c++){
    float s = p0*gw[c*HD + lane] + p1*gw[c*HD + 64 + lane];
    #pragma unroll
    for (int off=32; off>0; off>>=1) s += __shfl_down(s, off, 64);
    vals[c] = s;
  }
  if (lane == 0){
    float mx = -1e30f;
    #pragma unroll
    for (int c=0;c<NC;c++){ vals[c] += gb[c]; mx = fmaxf(mx, vals[c]); }
    float se = 0.f;
    #pragma unroll
    for (int c=0;c<NC;c++) se += __expf(vals[c] - mx);
    float lse = mx + __logf(se);
    #pragma unroll
    for (int c=0;c<NC;c++) out[g*NC + c] = vals[c] - lse;
  }
}

extern "C" void kernel_launch(void* const* d_in, const int* in_sizes, int n_in,
                              void* d_out, int out_size, void* d_ws, size_t ws_size,
                              hipStream_t stream)
{
  const float* x        = (const float*)d_in[0];
  const int*   ei       = (const int*)  d_in[1];
  const int*   batch    = (const int*)  d_in[2];
  const float* W        = (const float*)d_in[3];
  const float* w_ih     = (const float*)d_in[4];
  const float* w_hh     = (const float*)d_in[5];
  const float* b_ih     = (const float*)d_in[6];
  const float* b_hh     = (const float*)d_in[7];
  const float* local_w  = (const float*)d_in[8];
  const float* local_b  = (const float*)d_in[9];
  const float* global_w = (const float*)d_in[10];
  const float* global_b = (const float*)d_in[11];
  float* out = (float*)d_out;

  float* ws = (float*)d_ws;
  float* h      = ws;                      // 6,400,000 f
  float* m      = h + 6400000;             // 6,400,000 f
  float* aggr   = m + 6400000;             // 6,400,000 f
  float* wT_ih  = aggr + 6400000;          // 49,152 f
  float* wT_hh  = wT_ih + 49152;           // 49,152 f
  float* lwT    = wT_hh + 49152;           // 16,384 f
  float* pooled = lwT + 16384;             // 32,768 f
  float* cntf   = pooled + 32768;          // 256 f
  int* row_ptr  = (int*)(cntf + 256);      // NN+1
  int* cursor   = row_ptr + (NN + 1);      // NN
  int* csr_src  = cursor + NN;             // NE

  const int* esrc = ei;
  const int* edst = ei + NE;

  // CSR build (once per launch, reused for all 4 layers)
  hipMemsetAsync(cursor, 0, NN*sizeof(int), stream);
  prep_transpose<<<448, 256, 0, stream>>>(w_ih, w_hh, local_w, wT_ih, wT_hh, lwT);
  count_deg<<<3125, 256, 0, stream>>>(edst, cursor);
  scan_kernel<<<1, 1024, 0, stream>>>(cursor, row_ptr);
  fill_csr<<<3125, 256, 0, stream>>>(esrc, edst, cursor, csr_src);

  const float* hin = x;
  for (int l = 0; l < NL; l++){
    gemm_nodes<<<782, 256, 0, stream>>>(hin, W + (size_t)l*HD*HD, m);
    aggregate<<<12500, 256, 0, stream>>>(m, row_ptr, csr_src, aggr);
    gru_fused<<<1563, 256, 0, stream>>>(aggr, hin, wT_ih, wT_hh, b_ih, b_hh, h);
    hin = h;
  }

  hipMemsetAsync(pooled, 0, (32768 + 256)*sizeof(float), stream);
  local_pool<<<782, 256, 0, stream>>>(h, lwT, local_b, batch, pooled, cntf);
  classifier_kernel<<<NG, 64, 0, stream>>>(pooled, cntf, global_w, global_b, out);
}

// Round 2
// 1458.307 us; speedup vs baseline: 1.1800x; 1.1800x over previous
//
#include <hip/hip_runtime.h>

#define NN 50000
#define NE 800000
#define HD 128
#define NL 4
#define NC 10
#define NG 256

__device__ __forceinline__ float sigmf(float x){ return 1.0f/(1.0f + __expf(-x)); }
__device__ __forceinline__ float tanhff(float x){ return 2.0f/(1.0f + __expf(-2.0f*x)) - 1.0f; }

__device__ __forceinline__ void fma4(float4& acc, float s, const float4 b){
  acc.x = fmaf(s, b.x, acc.x);
  acc.y = fmaf(s, b.y, acc.y);
  acc.z = fmaf(s, b.z, acc.z);
  acc.w = fmaf(s, b.w, acc.w);
}

// ---------------- prep: transpose weights to [k][n] layouts ----------------
__global__ __launch_bounds__(256) void prep_transpose(
    const float* __restrict__ w_ih, const float* __restrict__ w_hh,
    const float* __restrict__ local_w,
    float* __restrict__ wT_ih, float* __restrict__ wT_hh, float* __restrict__ lwT)
{
  int idx = blockIdx.x*256 + threadIdx.x;
  if (idx < 49152){
    int k = idx/384, n = idx - k*384;
    wT_ih[idx] = w_ih[n*128 + k];
  } else if (idx < 98304){
    int j = idx - 49152;
    int k = j/384, n = j - k*384;
    wT_hh[j] = w_hh[n*128 + k];
  } else if (idx < 114688){
    int j = idx - 98304;
    int k = j >> 7, n = j & 127;
    lwT[j] = local_w[n*128 + k];
  }
}

// ---------------- CSR build ----------------
__global__ __launch_bounds__(256) void count_deg(const int* __restrict__ dst, int* deg)
{
  int e = blockIdx.x*256 + threadIdx.x;
  if (e < NE) atomicAdd(&deg[dst[e]], 1);
}

__global__ __launch_bounds__(1024) void scan_kernel(int* degcur, int* __restrict__ row_ptr)
{
  __shared__ int sdata[1024];
  __shared__ int carry_s;
  int t = threadIdx.x;
  if (t == 0) carry_s = 0;
  __syncthreads();
  for (int base = 0; base < NN; base += 1024){
    int v = (base + t < NN) ? degcur[base + t] : 0;
    sdata[t] = v;
    __syncthreads();
    for (int off = 1; off < 1024; off <<= 1){
      int x = (t >= off) ? sdata[t - off] : 0;
      __syncthreads();
      sdata[t] += x;
      __syncthreads();
    }
    int excl = sdata[t] - v;
    int c = carry_s;
    if (base + t < NN){
      row_ptr[base + t] = c + excl;
      degcur[base + t]  = c + excl;
    }
    __syncthreads();
    if (t == 0) carry_s = c + sdata[1023];
    __syncthreads();
  }
  if (t == 0) row_ptr[NN] = carry_s;
}

__global__ __launch_bounds__(256) void fill_csr(
    const int* __restrict__ src, const int* __restrict__ dst,
    int* cursor, int* __restrict__ csr_src)
{
  int e = blockIdx.x*256 + threadIdx.x;
  if (e < NE){
    int pos = atomicAdd(&cursor[dst[e]], 1);
    csr_src[pos] = src[e];
  }
}

// ---------------- graph_ptr: lower_bound of g in sorted batch ----------------
__global__ __launch_bounds__(64) void graph_ptr_kernel(const int* __restrict__ batch, int* __restrict__ gptr)
{
  int g = blockIdx.x*64 + threadIdx.x;
  if (g > NG) return;
  int lo = 0, hi = NN;
  while (lo < hi){
    int mid = (lo + hi) >> 1;
    if (batch[mid] < g) lo = mid + 1; else hi = mid;
  }
  gptr[g] = lo;
}

// ---------------- K1: C[n][f] = sum_k A[n][k] * B[k][f]; B is 128x128 [k][f] ----------------
__global__ __launch_bounds__(256) void gemm_nodes(
    const float* __restrict__ A, const float* __restrict__ B, float* __restrict__ Cc)
{
  __shared__ float a_s[64*36];
  __shared__ float b_s[32*128];
  int t = threadIdx.x;
  int tx = t & 15, ty = t >> 4;
  int f0 = tx*8;
  int nb = blockIdx.x * 64;
  float4 acc0[4], acc1[4];
  #pragma unroll
  for (int i=0;i<4;i++){ acc0[i]=make_float4(0,0,0,0); acc1[i]=make_float4(0,0,0,0); }

  for (int kc = 0; kc < 4; kc++){
    #pragma unroll
    for (int q=0;q<2;q++){
      int idx4 = t*2 + q;
      int node = idx4 >> 3;
      int kk4 = (idx4 & 7) * 4;
      int ng = nb + node;
      float4 val = make_float4(0,0,0,0);
      if (ng < NN) val = *(const float4*)&A[(size_t)ng*HD + kc*32 + kk4];
      *(float4*)&a_s[node*36 + kk4] = val;
    }
    #pragma unroll
    for (int q=0;q<4;q++){
      int idx4 = q*256 + t;
      int flat = idx4*4;
      int kk = flat >> 7, f = flat & 127;
      *(float4*)&b_s[kk*128 + f] = *(const float4*)&B[(kc*32+kk)*128 + f];
    }
    __syncthreads();
    #pragma unroll 8
    for (int kk = 0; kk < 32; kk++){
      float a_[4];
      #pragma unroll
      for (int i=0;i<4;i++) a_[i] = a_s[(ty*4+i)*36 + kk];
      float4 b0 = *(float4*)&b_s[kk*128 + f0];
      float4 b1 = *(float4*)&b_s[kk*128 + f0 + 4];
      #pragma unroll
      for (int i=0;i<4;i++){ fma4(acc0[i], a_[i], b0); fma4(acc1[i], a_[i], b1); }
    }
    __syncthreads();
  }
  #pragma unroll
  for (int i=0;i<4;i++){
    int n = nb + ty*4 + i;
    if (n < NN){
      *(float4*)&Cc[(size_t)n*HD + f0]     = acc0[i];
      *(float4*)&Cc[(size_t)n*HD + f0 + 4] = acc1[i];
    }
  }
}

// ---------------- K1b: local head GEMM + bias + ReLU -> local buffer ----------------
__global__ __launch_bounds__(256) void local_gemm(
    const float* __restrict__ A, const float* __restrict__ B,
    const float* __restrict__ bias, float* __restrict__ Cc)
{
  __shared__ float a_s[64*36];
  __shared__ float b_s[32*128];
  int t = threadIdx.x;
  int tx = t & 15, ty = t >> 4;
  int f0 = tx*8;
  int nb = blockIdx.x * 64;
  float4 acc0[4], acc1[4];
  #pragma unroll
  for (int i=0;i<4;i++){ acc0[i]=make_float4(0,0,0,0); acc1[i]=make_float4(0,0,0,0); }

  for (int kc = 0; kc < 4; kc++){
    #pragma unroll
    for (int q=0;q<2;q++){
      int idx4 = t*2 + q;
      int node = idx4 >> 3;
      int kk4 = (idx4 & 7) * 4;
      int ng = nb + node;
      float4 val = make_float4(0,0,0,0);
      if (ng < NN) val = *(const float4*)&A[(size_t)ng*HD + kc*32 + kk4];
      *(float4*)&a_s[node*36 + kk4] = val;
    }
    #pragma unroll
    for (int q=0;q<4;q++){
      int idx4 = q*256 + t;
      int flat = idx4*4;
      int kk = flat >> 7, f = flat & 127;
      *(float4*)&b_s[kk*128 + f] = *(const float4*)&B[(kc*32+kk)*128 + f];
    }
    __syncthreads();
    #pragma unroll 8
    for (int kk = 0; kk < 32; kk++){
      float a_[4];
      #pragma unroll
      for (int i=0;i<4;i++) a_[i] = a_s[(ty*4+i)*36 + kk];
      float4 b0 = *(float4*)&b_s[kk*128 + f0];
      float4 b1 = *(float4*)&b_s[kk*128 + f0 + 4];
      #pragma unroll
      for (int i=0;i<4;i++){ fma4(acc0[i], a_[i], b0); fma4(acc1[i], a_[i], b1); }
    }
    __syncthreads();
  }
  float4 bv0 = *(const float4*)&bias[f0];
  float4 bv1 = *(const float4*)&bias[f0 + 4];
  #pragma unroll
  for (int i=0;i<4;i++){
    int n = nb + ty*4 + i;
    if (n < NN){
      float4 r0, r1;
      r0.x = fmaxf(acc0[i].x + bv0.x, 0.f);
      r0.y = fmaxf(acc0[i].y + bv0.y, 0.f);
      r0.z = fmaxf(acc0[i].z + bv0.z, 0.f);
      r0.w = fmaxf(acc0[i].w + bv0.w, 0.f);
      r1.x = fmaxf(acc1[i].x + bv1.x, 0.f);
      r1.y = fmaxf(acc1[i].y + bv1.y, 0.f);
      r1.z = fmaxf(acc1[i].z + bv1.z, 0.f);
      r1.w = fmaxf(acc1[i].w + bv1.w, 0.f);
      *(float4*)&Cc[(size_t)n*HD + f0]     = r0;
      *(float4*)&Cc[(size_t)n*HD + f0 + 4] = r1;
    }
  }
}

// ---------------- K2: aggr[n] = sum over incoming edges of m[src] ----------------
__global__ __launch_bounds__(256) void aggregate(
    const float* __restrict__ m, const int* __restrict__ row_ptr,
    const int* __restrict__ csr_src, float* __restrict__ aggr)
{
  int nid = blockIdx.x*4 + (threadIdx.x >> 6);
  int lane = threadIdx.x & 63;
  if (nid >= NN) return;
  int s0 = row_ptr[nid], s1 = row_ptr[nid+1];
  float2 acc = make_float2(0.f, 0.f);
  const float2* m2 = (const float2*)m;
  for (int j = s0; j < s1; j++){
    int s = csr_src[j];
    float2 v = m2[(size_t)s*64 + lane];
    acc.x += v.x; acc.y += v.y;
  }
  ((float2*)aggr)[(size_t)nid*64 + lane] = acc;
}

// ---------------- K3: fused GRU cell ----------------
__global__ __launch_bounds__(256) void gru_fused(
    const float* __restrict__ aggr, const float* h_in,
    const float* __restrict__ wT_ih, const float* __restrict__ wT_hh,
    const float* __restrict__ b_ih, const float* __restrict__ b_hh,
    float* h_out)
{
  __shared__ float a_s[32*20];
  __shared__ float h_s[32*20];
  __shared__ float w_s[6*16*128];
  int t = threadIdx.x;
  int tx = t & 31, ty = t >> 5;
  int f0 = tx*4;
  int nb = blockIdx.x*32;
  float4 sr[4], sz[4], gin[4], ghn[4];
  #pragma unroll
  for (int i=0;i<4;i++){
    sr[i]=make_float4(0,0,0,0); sz[i]=make_float4(0,0,0,0);
    gin[i]=make_float4(0,0,0,0); ghn[i]=make_float4(0,0,0,0);
  }

  for (int kc = 0; kc < 8; kc++){
    {
      int idx4 = t & 127;
      int node = idx4 >> 2;
      int kk4 = (idx4 & 3) * 4;
      int ng = nb + node;
      const float* srcp = (t < 128) ? aggr : h_in;
      float* dstp = (t < 128) ? a_s : h_s;
      float4 val = make_float4(0,0,0,0);
      if (ng < NN) val = *(const float4*)&srcp[(size_t)ng*HD + kc*16 + kk4];
      *(float4*)&dstp[node*20 + kk4] = val;
    }
    #pragma unroll
    for (int q=0; q<12; q++){
      int idx4 = q*256 + t;
      int flat = idx4*4;
      int mi = flat >> 11;
      int rem = flat & 2047;
      int kk = rem >> 7;
      int f = rem & 127;
      const float* wsrc = (mi < 3) ? wT_ih : wT_hh;
      int gate = (mi < 3) ? mi : (mi-3);
      *(float4*)&w_s[mi*2048 + kk*128 + f] = *(const float4*)&wsrc[(kc*16+kk)*384 + gate*128 + f];
    }
    __syncthreads();
    #pragma unroll 4
    for (int kk = 0; kk < 16; kk++){
      float a_[4], hh_[4];
      #pragma unroll
      for (int i=0;i<4;i++){
        a_[i]  = a_s[(ty*4+i)*20 + kk];
        hh_[i] = h_s[(ty*4+i)*20 + kk];
      }
      const float4 wir = *(const float4*)&w_s[        kk*128 + f0];
      const float4 wiz = *(const float4*)&w_s[2048 +  kk*128 + f0];
      const float4 win = *(const float4*)&w_s[4096 +  kk*128 + f0];
      const float4 whr = *(const float4*)&w_s[6144 +  kk*128 + f0];
      const float4 whz = *(const float4*)&w_s[8192 +  kk*128 + f0];
      const float4 whn = *(const float4*)&w_s[10240 + kk*128 + f0];
      #pragma unroll
      for (int i=0;i<4;i++){
        fma4(sr[i],  a_[i],  wir); fma4(sr[i],  hh_[i], whr);
        fma4(sz[i],  a_[i],  wiz); fma4(sz[i],  hh_[i], whz);
        fma4(gin[i], a_[i],  win);
        fma4(ghn[i], hh_[i], whn);
      }
    }
    __syncthreads();
  }

  float4 bir = *(const float4*)&b_ih[f0];
  float4 biz = *(const float4*)&b_ih[128 + f0];
  float4 bin = *(const float4*)&b_ih[256 + f0];
  float4 bhr = *(const float4*)&b_hh[f0];
  float4 bhz = *(const float4*)&b_hh[128 + f0];
  float4 bhn = *(const float4*)&b_hh[256 + f0];

  #pragma unroll
  for (int i=0;i<4;i++){
    int n = nb + ty*4 + i;
    if (n >= NN) continue;
    float4 ho = *(const float4*)&h_in[(size_t)n*HD + f0];
    float4 hn;
    {
      float r  = sigmf(sr[i].x + bir.x + bhr.x);
      float zg = sigmf(sz[i].x + biz.x + bhz.x);
      float ng_ = tanhff(gin[i].x + bin.x + r*(ghn[i].x + bhn.x));
      hn.x = (1.0f - zg)*ng_ + zg*ho.x;
    }
    {
      float r  = sigmf(sr[i].y + bir.y + bhr.y);
      float zg = sigmf(sz[i].y + biz.y + bhz.y);
      float ng_ = tanhff(gin[i].y + bin.y + r*(ghn[i].y + bhn.y));
      hn.y = (1.0f - zg)*ng_ + zg*ho.y;
    }
    {
      float r  = sigmf(sr[i].z + bir.z + bhr.z);
      float zg = sigmf(sz[i].z + biz.z + bhz.z);
      float ng_ = tanhff(gin[i].z + bin.z + r*(ghn[i].z + bhn.z));
      hn.z = (1.0f - zg)*ng_ + zg*ho.z;
    }
    {
      float r  = sigmf(sr[i].w + bir.w + bhr.w);
      float zg = sigmf(sz[i].w + biz.w + bhz.w);
      float ng_ = tanhff(gin[i].w + bin.w + r*(ghn[i].w + bhn.w));
      hn.w = (1.0f - zg)*ng_ + zg*ho.w;
    }
    *(float4*)&h_out[(size_t)n*HD + f0] = hn;
  }
}

// ---------------- segmented mean-pool: one block per graph, zero atomics ----------------
__global__ __launch_bounds__(256) void pool_kernel(
    const float* __restrict__ local, const int* __restrict__ gptr,
    float* __restrict__ pooled)
{
  __shared__ float4 red[8][32];
  int g = blockIdx.x;
  int lane = threadIdx.x & 31;
  int st = threadIdx.x >> 5;           // 8 node-streams
  int s0 = gptr[g], s1 = gptr[g+1];
  float4 acc = make_float4(0,0,0,0);
  for (int n = s0 + st; n < s1; n += 8){
    float4 v = *(const float4*)&local[(size_t)n*HD + lane*4];
    acc.x += v.x; acc.y += v.y; acc.z += v.z; acc.w += v.w;
  }
  red[st][lane] = acc;
  __syncthreads();
  if (st == 0){
    float4 s = red[0][lane];
    #pragma unroll
    for (int i=1;i<8;i++){
      float4 v = red[i][lane];
      s.x += v.x; s.y += v.y; s.z += v.z; s.w += v.w;
    }
    float cnt = (float)(s1 - s0);
    if (cnt < 1.0f) cnt = 1.0f;
    float inv = 1.0f / cnt;
    s.x *= inv; s.y *= inv; s.z *= inv; s.w *= inv;
    *(float4*)&pooled[g*HD + lane*4] = s;
  }
}

// ---------------- classifier + log_softmax (pooled already averaged) ----------------
__global__ __launch_bounds__(64) void classifier_kernel(
    const float* __restrict__ pooled,
    const float* __restrict__ gw, const float* __restrict__ gb,
    float* __restrict__ out)
{
  int g = blockIdx.x;
  int lane = threadIdx.x;
  float p0 = pooled[g*HD + lane];
  float p1 = pooled[g*HD + 64 + lane];
  float vals[NC];
  #pragma unroll
  for (int c=0;c<NC;c++){
    float s = p0*gw[c*HD + lane] + p1*gw[c*HD + 64 + lane];
    #pragma unroll
    for (int off=32; off>0; off>>=1) s += __shfl_down(s, off, 64);
    vals[c] = s;
  }
  if (lane == 0){
    float mx = -1e30f;
    #pragma unroll
    for (int c=0;c<NC;c++){ vals[c] += gb[c]; mx = fmaxf(mx, vals[c]); }
    float se = 0.f;
    #pragma unroll
    for (int c=0;c<NC;c++) se += __expf(vals[c] - mx);
    float lse = mx + __logf(se);
    #pragma unroll
    for (int c=0;c<NC;c++) out[g*NC + c] = vals[c] - lse;
  }
}

extern "C" void kernel_launch(void* const* d_in, const int* in_sizes, int n_in,
                              void* d_out, int out_size, void* d_ws, size_t ws_size,
                              hipStream_t stream)
{
  const float* x        = (const float*)d_in[0];
  const int*   ei       = (const int*)  d_in[1];
  const int*   batch    = (const int*)  d_in[2];
  const float* W        = (const float*)d_in[3];
  const float* w_ih     = (const float*)d_in[4];
  const float* w_hh     = (const float*)d_in[5];
  const float* b_ih     = (const float*)d_in[6];
  const float* b_hh     = (const float*)d_in[7];
  const float* local_w  = (const float*)d_in[8];
  const float* local_b  = (const float*)d_in[9];
  const float* global_w = (const float*)d_in[10];
  const float* global_b = (const float*)d_in[11];
  float* out = (float*)d_out;

  float* ws = (float*)d_ws;
  float* h      = ws;                      // 6,400,000 f
  float* m      = h + 6400000;             // 6,400,000 f (also reused as `local`)
  float* aggr   = m + 6400000;             // 6,400,000 f
  float* wT_ih  = aggr + 6400000;          // 49,152 f
  float* wT_hh  = wT_ih + 49152;           // 49,152 f
  float* lwT    = wT_hh + 49152;           // 16,384 f
  float* pooled = lwT + 16384;             // 32,768 f
  int* row_ptr  = (int*)(pooled + 32768);  // NN+1
  int* cursor   = row_ptr + (NN + 1);      // NN
  int* csr_src  = cursor + NN;             // NE
  int* gptr     = csr_src + NE;            // NG+1

  const int* esrc = ei;
  const int* edst = ei + NE;

  // CSR build (once per launch, reused for all 4 layers)
  hipMemsetAsync(cursor, 0, NN*sizeof(int), stream);
  prep_transpose<<<448, 256, 0, stream>>>(w_ih, w_hh, local_w, wT_ih, wT_hh, lwT);
  count_deg<<<3125, 256, 0, stream>>>(edst, cursor);
  scan_kernel<<<1, 1024, 0, stream>>>(cursor, row_ptr);
  fill_csr<<<3125, 256, 0, stream>>>(esrc, edst, cursor, csr_src);
  graph_ptr_kernel<<<5, 64, 0, stream>>>(batch, gptr);

  const float* hin = x;
  for (int l = 0; l < NL; l++){
    gemm_nodes<<<782, 256, 0, stream>>>(hin, W + (size_t)l*HD*HD, m);
    aggregate<<<12500, 256, 0, stream>>>(m, row_ptr, csr_src, aggr);
    gru_fused<<<1563, 256, 0, stream>>>(aggr, hin, wT_ih, wT_hh, b_ih, b_hh, h);
    hin = h;
  }

  // local head -> m (reused), then segmented mean-pool, then classifier
  local_gemm<<<782, 256, 0, stream>>>(h, lwT, local_b, m);
  pool_kernel<<<NG, 256, 0, stream>>>(m, gptr, pooled);
  classifier_kernel<<<NG, 64, 0, stream>>>(pooled, global_w, global_b, out);
}

// Round 3
// 953.983 us; speedup vs baseline: 1.8037x; 1.5287x over previous
//
#include <hip/hip_runtime.h>

#define NN 50000
#define NE 800000
#define HD 128
#define NL 4
#define NC 10
#define NG 256

typedef __attribute__((ext_vector_type(8))) short short8;    // 8 bf16 = 4 VGPR (MFMA A/B frag)
typedef __attribute__((ext_vector_type(4))) float floatx4;   // MFMA C/D frag

union frg { uint4 u; short8 s; };

__device__ __forceinline__ short8 load_frag(const ushort* p){
  frg f; f.u = *(const uint4*)p; return f.s;
}
__device__ __forceinline__ short8 zero_frag(){
  frg f; f.u = make_uint4(0,0,0,0); return f.s;
}
__device__ __forceinline__ floatx4 MFMA(short8 a, short8 b, floatx4 c){
  return __builtin_amdgcn_mfma_f32_16x16x32_bf16(a, b, c, 0, 0, 0);
}

__device__ __forceinline__ ushort f2bf(float x){           // RNE fp32->bf16
  unsigned u = __float_as_uint(x);
  return (ushort)((u + 0x7FFFu + ((u >> 16) & 1u)) >> 16);
}
__device__ __forceinline__ float sigmf(float x){ return 1.0f/(1.0f + __expf(-x)); }
__device__ __forceinline__ float tanhff(float x){ return 2.0f/(1.0f + __expf(-2.0f*x)) - 1.0f; }

// ---------------- prep: convert weights to bf16 (W also transposed to [f][k]) ----------------
__global__ __launch_bounds__(256) void prep_weights_bf16(
    const float* __restrict__ w_ih, const float* __restrict__ w_hh,
    const float* __restrict__ W, const float* __restrict__ local_w,
    ushort* __restrict__ wih_bf, ushort* __restrict__ whh_bf,
    ushort* __restrict__ WT_bf, ushort* __restrict__ lw_bf)
{
  int idx = blockIdx.x*256 + threadIdx.x;
  if (idx < 49152) wih_bf[idx] = f2bf(w_ih[idx]);
  else if (idx < 98304){ int j = idx - 49152; whh_bf[j] = f2bf(w_hh[j]); }
  else if (idx < 163840){
    int j = idx - 98304;                 // 4 * 128 * 128, output layout [l][f][k]
    int l = j >> 14, rem = j & 16383;
    int f = rem >> 7, k = rem & 127;
    WT_bf[j] = f2bf(W[l*16384 + k*128 + f]);
  } else if (idx < 180224){
    int j = idx - 163840;
    lw_bf[j] = f2bf(local_w[j]);
  }
}

__global__ __launch_bounds__(256) void convert_x(const float4* __restrict__ x, ushort4* __restrict__ xbf)
{
  int i = blockIdx.x*256 + threadIdx.x;
  if (i < NN*HD/4){
    float4 v = x[i];
    ushort4 o; o.x=f2bf(v.x); o.y=f2bf(v.y); o.z=f2bf(v.z); o.w=f2bf(v.w);
    xbf[i] = o;
  }
}

// ---------------- CSR build ----------------
__global__ __launch_bounds__(256) void count_deg(const int* __restrict__ dst, int* deg)
{
  int e = blockIdx.x*256 + threadIdx.x;
  if (e < NE) atomicAdd(&deg[dst[e]], 1);
}

__global__ __launch_bounds__(1024) void scan_kernel(int* degcur, int* __restrict__ row_ptr)
{
  __shared__ int sdata[1024];
  __shared__ int carry_s;
  int t = threadIdx.x;
  if (t == 0) carry_s = 0;
  __syncthreads();
  for (int base = 0; base < NN; base += 1024){
    int v = (base + t < NN) ? degcur[base + t] : 0;
    sdata[t] = v;
    __syncthreads();
    for (int off = 1; off < 1024; off <<= 1){
      int x = (t >= off) ? sdata[t - off] : 0;
      __syncthreads();
      sdata[t] += x;
      __syncthreads();
    }
    int excl = sdata[t] - v;
    int c = carry_s;
    if (base + t < NN){
      row_ptr[base + t] = c + excl;
      degcur[base + t]  = c + excl;
    }
    __syncthreads();
    if (t == 0) carry_s = c + sdata[1023];
    __syncthreads();
  }
  if (t == 0) row_ptr[NN] = carry_s;
}

__global__ __launch_bounds__(256) void fill_csr(
    const int* __restrict__ src, const int* __restrict__ dst,
    int* cursor, int* __restrict__ csr_src)
{
  int e = blockIdx.x*256 + threadIdx.x;
  if (e < NE){
    int pos = atomicAdd(&cursor[dst[e]], 1);
    csr_src[pos] = src[e];
  }
}

__global__ __launch_bounds__(64) void graph_ptr_kernel(const int* __restrict__ batch, int* __restrict__ gptr)
{
  int g = blockIdx.x*64 + threadIdx.x;
  if (g > NG) return;
  int lo = 0, hi = NN;
  while (lo < hi){
    int mid = (lo + hi) >> 1;
    if (batch[mid] < g) lo = mid + 1; else hi = mid;
  }
  gptr[g] = lo;
}

// ---------------- K1: m = hbf @ W[l]  (MFMA, B^T = WT_bf [f][k]) -> bf16 ----------------
// one wave per 16-node tile, all 128 features (8 f-tiles)
__global__ __launch_bounds__(256) void gemm_m_bf16(
    const ushort* __restrict__ Abf, const ushort* __restrict__ Bt,
    ushort* __restrict__ Mout)
{
  int wv = threadIdx.x >> 6, lane = threadIdx.x & 63;
  int mt = blockIdx.x*4 + wv;
  if (mt >= NN/16) return;
  int m0 = mt*16, mrow = lane & 15, quad = lane >> 4;
  floatx4 acc[8] = {};
  for (int kc = 0; kc < 4; kc++){
    int k0 = kc*32 + quad*8;
    short8 a = load_frag(&Abf[(size_t)(m0 + mrow)*HD + k0]);
    #pragma unroll
    for (int ft = 0; ft < 8; ft++){
      short8 b = load_frag(&Bt[(size_t)(ft*16 + mrow)*HD + k0]);
      acc[ft] = MFMA(a, b, acc[ft]);
    }
  }
  #pragma unroll
  for (int ft = 0; ft < 8; ft++){
    #pragma unroll
    for (int r = 0; r < 4; r++){
      int n = m0 + quad*4 + r;
      Mout[(size_t)n*HD + ft*16 + mrow] = f2bf(acc[ft][r]);
    }
  }
}

// ---------------- K2: aggr[n] = sum_{e: dst=n} m[src]  (bf16 in, bf16 out) ----------------
__global__ __launch_bounds__(256) void aggregate_bf16(
    const uint* __restrict__ m, const int* __restrict__ row_ptr,
    const int* __restrict__ csr_src, uint* __restrict__ aggr)
{
  int nid = blockIdx.x*4 + (threadIdx.x >> 6);
  int lane = threadIdx.x & 63;
  if (nid >= NN) return;
  int s0 = row_ptr[nid], s1 = row_ptr[nid+1];
  float ax = 0.f, ay = 0.f;
  for (int j = s0; j < s1; j++){
    int s = csr_src[j];
    uint v = m[(size_t)s*64 + lane];
    ax += __uint_as_float(v << 16);
    ay += __uint_as_float(v & 0xFFFF0000u);
  }
  aggr[(size_t)nid*64 + lane] = (uint)f2bf(ax) | ((uint)f2bf(ay) << 16);
}

// ---------------- K3: fused GRU via MFMA ----------------
// block = 4 waves, 32 nodes (2 m-tiles); wave wv covers features [wv*32, wv*32+32) (2 f-tiles)
// acc groups: r (aggr@wih_r + h@whh_r), z (likewise), i_n (aggr@wih_n), h_n (h@whh_n)
__global__ __launch_bounds__(256) void gru_mfma(
    const ushort* __restrict__ aggr_bf, const ushort* __restrict__ h_bf,
    const float* __restrict__ h_f32,
    const ushort* __restrict__ wih_bf, const ushort* __restrict__ whh_bf,
    const float* __restrict__ b_ih, const float* __restrict__ b_hh,
    float* __restrict__ hout_f32, ushort* __restrict__ hout_bf)
{
  int wv = threadIdx.x >> 6, lane = threadIdx.x & 63;
  int mrow = lane & 15, quad = lane >> 4;
  int m0 = blockIdx.x * 32;
  bool v1 = (m0 + 16) < NN;
  floatx4 aR[2][2] = {}, aZ[2][2] = {}, aIN[2][2] = {}, aHN[2][2] = {};

  for (int kc = 0; kc < 4; kc++){
    int k0 = kc*32 + quad*8;
    short8 fa[2], fh[2];
    fa[0] = load_frag(&aggr_bf[(size_t)(m0 + mrow)*HD + k0]);
    fh[0] = load_frag(&h_bf  [(size_t)(m0 + mrow)*HD + k0]);
    if (v1){
      fa[1] = load_frag(&aggr_bf[(size_t)(m0 + 16 + mrow)*HD + k0]);
      fh[1] = load_frag(&h_bf  [(size_t)(m0 + 16 + mrow)*HD + k0]);
    } else { fa[1] = zero_frag(); fh[1] = zero_frag(); }
    #pragma unroll
    for (int ftl = 0; ftl < 2; ftl++){
      size_t wo = (size_t)((wv*2 + ftl)*16 + mrow)*HD + k0;
      short8 wir = load_frag(&wih_bf[wo]);
      short8 wiz = load_frag(&wih_bf[128*HD + wo]);
      short8 win = load_frag(&wih_bf[256*HD + wo]);
      short8 whr = load_frag(&whh_bf[wo]);
      short8 whz = load_frag(&whh_bf[128*HD + wo]);
      short8 whn = load_frag(&whh_bf[256*HD + wo]);
      #pragma unroll
      for (int i = 0; i < 2; i++){
        aR[i][ftl]  = MFMA(fa[i], wir, aR[i][ftl]);
        aR[i][ftl]  = MFMA(fh[i], whr, aR[i][ftl]);
        aZ[i][ftl]  = MFMA(fa[i], wiz, aZ[i][ftl]);
        aZ[i][ftl]  = MFMA(fh[i], whz, aZ[i][ftl]);
        aIN[i][ftl] = MFMA(fa[i], win, aIN[i][ftl]);
        aHN[i][ftl] = MFMA(fh[i], whn, aHN[i][ftl]);
      }
    }
  }

  #pragma unroll
  for (int ftl = 0; ftl < 2; ftl++){
    int feat = (wv*2 + ftl)*16 + mrow;
    float bir = b_ih[feat], biz = b_ih[128+feat], bin = b_ih[256+feat];
    float bhr = b_hh[feat], bhz = b_hh[128+feat], bhn = b_hh[256+feat];
    #pragma unroll
    for (int i = 0; i < 2; i++){
      if (i == 1 && !v1) break;
      #pragma unroll
      for (int r = 0; r < 4; r++){
        int node = m0 + i*16 + quad*4 + r;
        float rr = sigmf(aR[i][ftl][r] + bir + bhr);
        float zz = sigmf(aZ[i][ftl][r] + biz + bhz);
        float nn = tanhff(aIN[i][ftl][r] + bin + rr*(aHN[i][ftl][r] + bhn));
        float ho = h_f32[(size_t)node*HD + feat];
        float hv = (1.f - zz)*nn + zz*ho;
        hout_f32[(size_t)node*HD + feat] = hv;
        hout_bf [(size_t)node*HD + feat] = f2bf(hv);
      }
    }
  }
}

// ---------------- local head: relu(hbf @ local_w^T + b) -> fp32 ----------------
__global__ __launch_bounds__(256) void local_gemm_mfma(
    const ushort* __restrict__ hbf, const ushort* __restrict__ lw_bf,
    const float* __restrict__ bias, float* __restrict__ local)
{
  int wv = threadIdx.x >> 6, lane = threadIdx.x & 63;
  int mt = blockIdx.x*4 + wv;
  if (mt >= NN/16) return;
  int m0 = mt*16, mrow = lane & 15, quad = lane >> 4;
  floatx4 acc[8] = {};
  for (int kc = 0; kc < 4; kc++){
    int k0 = kc*32 + quad*8;
    short8 a = load_frag(&hbf[(size_t)(m0 + mrow)*HD + k0]);
    #pragma unroll
    for (int ft = 0; ft < 8; ft++){
      short8 b = load_frag(&lw_bf[(size_t)(ft*16 + mrow)*HD + k0]);
      acc[ft] = MFMA(a, b, acc[ft]);
    }
  }
  #pragma unroll
  for (int ft = 0; ft < 8; ft++){
    float bv = bias[ft*16 + mrow];
    #pragma unroll
    for (int r = 0; r < 4; r++){
      int n = m0 + quad*4 + r;
      local[(size_t)n*HD + ft*16 + mrow] = fmaxf(acc[ft][r] + bv, 0.f);
    }
  }
}

// ---------------- segmented mean-pool (batch sorted, zero atomics) ----------------
__global__ __launch_bounds__(256) void pool_kernel(
    const float* __restrict__ local, const int* __restrict__ gptr,
    float* __restrict__ pooled)
{
  __shared__ float4 red[8][32];
  int g = blockIdx.x;
  int lane = threadIdx.x & 31;
  int st = threadIdx.x >> 5;
  int s0 = gptr[g], s1 = gptr[g+1];
  float4 acc = make_float4(0,0,0,0);
  for (int n = s0 + st; n < s1; n += 8){
    float4 v = *(const float4*)&local[(size_t)n*HD + lane*4];
    acc.x += v.x; acc.y += v.y; acc.z += v.z; acc.w += v.w;
  }
  red[st][lane] = acc;
  __syncthreads();
  if (st == 0){
    float4 s = red[0][lane];
    #pragma unroll
    for (int i=1;i<8;i++){
      float4 v = red[i][lane];
      s.x += v.x; s.y += v.y; s.z += v.z; s.w += v.w;
    }
    float cnt = (float)(s1 - s0);
    if (cnt < 1.0f) cnt = 1.0f;
    float inv = 1.0f / cnt;
    s.x *= inv; s.y *= inv; s.z *= inv; s.w *= inv;
    *(float4*)&pooled[g*HD + lane*4] = s;
  }
}

// ---------------- classifier + log_softmax ----------------
__global__ __launch_bounds__(64) void classifier_kernel(
    const float* __restrict__ pooled,
    const float* __restrict__ gw, const float* __restrict__ gb,
    float* __restrict__ out)
{
  int g = blockIdx.x;
  int lane = threadIdx.x;
  float p0 = pooled[g*HD + lane];
  float p1 = pooled[g*HD + 64 + lane];
  float vals[NC];
  #pragma unroll
  for (int c=0;c<NC;c++){
    float s = p0*gw[c*HD + lane] + p1*gw[c*HD + 64 + lane];
    #pragma unroll
    for (int off=32; off>0; off>>=1) s += __shfl_down(s, off, 64);
    vals[c] = s;
  }
  if (lane == 0){
    float mx = -1e30f;
    #pragma unroll
    for (int c=0;c<NC;c++){ vals[c] += gb[c]; mx = fmaxf(mx, vals[c]); }
    float se = 0.f;
    #pragma unroll
    for (int c=0;c<NC;c++) se += __expf(vals[c] - mx);
    float lse = mx + __logf(se);
    #pragma unroll
    for (int c=0;c<NC;c++) out[g*NC + c] = vals[c] - lse;
  }
}

extern "C" void kernel_launch(void* const* d_in, const int* in_sizes, int n_in,
                              void* d_out, int out_size, void* d_ws, size_t ws_size,
                              hipStream_t stream)
{
  const float* x        = (const float*)d_in[0];
  const int*   ei       = (const int*)  d_in[1];
  const int*   batch    = (const int*)  d_in[2];
  const float* W        = (const float*)d_in[3];
  const float* w_ih     = (const float*)d_in[4];
  const float* w_hh     = (const float*)d_in[5];
  const float* b_ih     = (const float*)d_in[6];
  const float* b_hh     = (const float*)d_in[7];
  const float* local_w  = (const float*)d_in[8];
  const float* local_b  = (const float*)d_in[9];
  const float* global_w = (const float*)d_in[10];
  const float* global_b = (const float*)d_in[11];
  float* out = (float*)d_out;

  // workspace layout (bytes) — total ~81 MB
  char* base = (char*)d_ws;
  float*  h       = (float*)base;                     // 25.6 MB fp32 h master
  char*   R       = base + 25600000;                  // 25.6 MB: m_bf+aggr_bf, reused as local fp32
  ushort* m_bf    = (ushort*)R;                       // 12.8 MB
  ushort* aggr_bf = (ushort*)(R + 12800000);          // 12.8 MB
  float*  local   = (float*)R;                        // 25.6 MB (after GRU layers done)
  ushort* xbf     = (ushort*)(base + 51200000);       // 12.8 MB
  ushort* hbf     = (ushort*)(base + 64000000);       // 12.8 MB
  ushort* wih_bf  = (ushort*)(base + 76800000);       // 96 KB
  ushort* whh_bf  = wih_bf + 49152;
  ushort* WT_bf   = whh_bf + 49152;                   // 128 KB ([l][f][k])
  ushort* lw_bf   = WT_bf + 65536;
  float*  pooled  = (float*)(lw_bf + 16384);          // 128 KB
  int* row_ptr    = (int*)(pooled + 32768);           // NN+1
  int* cursor     = row_ptr + (NN + 1);               // NN
  int* csr_src    = cursor + NN;                      // NE
  int* gptr       = csr_src + NE;                     // NG+1

  const int* esrc = ei;
  const int* edst = ei + NE;

  hipMemsetAsync(cursor, 0, NN*sizeof(int), stream);
  prep_weights_bf16<<<704, 256, 0, stream>>>(w_ih, w_hh, W, local_w, wih_bf, whh_bf, WT_bf, lw_bf);
  convert_x<<<6250, 256, 0, stream>>>((const float4*)x, (ushort4*)xbf);
  count_deg<<<3125, 256, 0, stream>>>(edst, cursor);
  scan_kernel<<<1, 1024, 0, stream>>>(cursor, row_ptr);
  fill_csr<<<3125, 256, 0, stream>>>(esrc, edst, cursor, csr_src);
  graph_ptr_kernel<<<5, 64, 0, stream>>>(batch, gptr);

  const float*  hin_f = x;
  const ushort* hin_b = xbf;
  for (int l = 0; l < NL; l++){
    gemm_m_bf16<<<782, 256, 0, stream>>>(hin_b, WT_bf + l*16384, m_bf);
    aggregate_bf16<<<12500, 256, 0, stream>>>((const uint*)m_bf, row_ptr, csr_src, (uint*)aggr_bf);
    gru_mfma<<<1563, 256, 0, stream>>>(aggr_bf, hin_b, hin_f, wih_bf, whh_bf, b_ih, b_hh, h, hbf);
    hin_f = h; hin_b = hbf;
  }

  local_gemm_mfma<<<782, 256, 0, stream>>>(hbf, lw_bf, local_b, local);
  pool_kernel<<<NG, 256, 0, stream>>>(local, gptr, pooled);
  classifier_kernel<<<NG, 64, 0, stream>>>(pooled, global_w, global_b, out);
}

// Round 4
// 756.675 us; speedup vs baseline: 2.2741x; 1.2608x over previous
//
#include <hip/hip_runtime.h>

#define NN 50000
#define NE 800000
#define HD 128
#define NL 4
#define NC 10
#define NG 256

typedef __attribute__((ext_vector_type(8))) short short8;    // 8 bf16 = 4 VGPR (MFMA A/B frag)
typedef __attribute__((ext_vector_type(4))) float floatx4;   // MFMA C/D frag

union frg { uint4 u; short8 s; };

__device__ __forceinline__ short8 load_frag(const ushort* p){
  frg f; f.u = *(const uint4*)p; return f.s;
}
__device__ __forceinline__ short8 zero_frag(){
  frg f; f.u = make_uint4(0,0,0,0); return f.s;
}
__device__ __forceinline__ floatx4 MFMA(short8 a, short8 b, floatx4 c){
  return __builtin_amdgcn_mfma_f32_16x16x32_bf16(a, b, c, 0, 0, 0);
}

__device__ __forceinline__ ushort f2bf(float x){           // RNE fp32->bf16
  unsigned u = __float_as_uint(x);
  return (ushort)((u + 0x7FFFu + ((u >> 16) & 1u)) >> 16);
}
__device__ __forceinline__ float sigmf(float x){ return 1.0f/(1.0f + __expf(-x)); }
__device__ __forceinline__ float tanhff(float x){ return 2.0f/(1.0f + __expf(-2.0f*x)) - 1.0f; }

// ---------------- prep: convert weights to bf16 (W also transposed to [f][k]) ----------------
__global__ __launch_bounds__(256) void prep_weights_bf16(
    const float* __restrict__ w_ih, const float* __restrict__ w_hh,
    const float* __restrict__ W, const float* __restrict__ local_w,
    ushort* __restrict__ wih_bf, ushort* __restrict__ whh_bf,
    ushort* __restrict__ WT_bf, ushort* __restrict__ lw_bf)
{
  int idx = blockIdx.x*256 + threadIdx.x;
  if (idx < 49152) wih_bf[idx] = f2bf(w_ih[idx]);
  else if (idx < 98304){ int j = idx - 49152; whh_bf[j] = f2bf(w_hh[j]); }
  else if (idx < 163840){
    int j = idx - 98304;                 // 4 * 128 * 128, output layout [l][f][k]
    int l = j >> 14, rem = j & 16383;
    int f = rem >> 7, k = rem & 127;
    WT_bf[j] = f2bf(W[l*16384 + k*128 + f]);
  } else if (idx < 180224){
    int j = idx - 163840;
    lw_bf[j] = f2bf(local_w[j]);
  }
}

__global__ __launch_bounds__(256) void convert_x(const float4* __restrict__ x, ushort4* __restrict__ xbf)
{
  int i = blockIdx.x*256 + threadIdx.x;
  if (i < NN*HD/4){
    float4 v = x[i];
    ushort4 o; o.x=f2bf(v.x); o.y=f2bf(v.y); o.z=f2bf(v.z); o.w=f2bf(v.w);
    xbf[i] = o;
  }
}

// ---------------- CSR build ----------------
__global__ __launch_bounds__(256) void count_deg(const int* __restrict__ dst, int* deg)
{
  int e = blockIdx.x*256 + threadIdx.x;
  if (e < NE) atomicAdd(&deg[dst[e]], 1);
}

// --- hierarchical scan: 49 blocks x 1024, wave-shuffle based ---
__global__ __launch_bounds__(1024) void scan_blocks(
    const int* __restrict__ deg, int* __restrict__ excl_out, int* __restrict__ bsum)
{
  __shared__ int wsum[16];
  int t = threadIdx.x;
  int gid = blockIdx.x*1024 + t;
  int v = (gid < NN) ? deg[gid] : 0;
  int lane = t & 63, wv = t >> 6;
  int incl = v;
  #pragma unroll
  for (int off=1; off<64; off<<=1){
    int y = __shfl_up(incl, off, 64);
    if (lane >= off) incl += y;
  }
  if (lane == 63) wsum[wv] = incl;
  __syncthreads();
  if (wv == 0){
    int s = (lane < 16) ? wsum[lane] : 0;
    #pragma unroll
    for (int off=1; off<16; off<<=1){
      int y = __shfl_up(s, off, 64);
      if (lane >= off) s += y;
    }
    if (lane < 16) wsum[lane] = s;         // inclusive wave-sums
  }
  __syncthreads();
  int wpre = (wv > 0) ? wsum[wv-1] : 0;
  if (gid < NN) excl_out[gid] = wpre + incl - v;
  if (t == 1023) bsum[blockIdx.x] = wpre + incl;
}

__global__ __launch_bounds__(64) void scan_carry(int* bsum, int* __restrict__ row_ptr)
{
  int lane = threadIdx.x;
  int v = (lane < 49) ? bsum[lane] : 0;
  int incl = v;
  #pragma unroll
  for (int off=1; off<64; off<<=1){
    int y = __shfl_up(incl, off, 64);
    if (lane >= off) incl += y;
  }
  if (lane < 49) bsum[lane] = incl - v;    // exclusive carry per block
  if (lane == 0) row_ptr[NN] = NE;
}

__global__ __launch_bounds__(1024) void scan_add(
    const int* __restrict__ bsum, int* __restrict__ row_ptr, int* __restrict__ cursor)
{
  int gid = blockIdx.x*1024 + threadIdx.x;
  if (gid < NN){
    int v = row_ptr[gid] + bsum[blockIdx.x];
    row_ptr[gid] = v;
    cursor[gid]  = v;
  }
}

__global__ __launch_bounds__(256) void fill_csr(
    const int* __restrict__ src, const int* __restrict__ dst,
    int* cursor, int* __restrict__ csr_src)
{
  int e = blockIdx.x*256 + threadIdx.x;
  if (e < NE){
    int pos = atomicAdd(&cursor[dst[e]], 1);
    csr_src[pos] = src[e];
  }
}

__global__ __launch_bounds__(64) void graph_ptr_kernel(const int* __restrict__ batch, int* __restrict__ gptr)
{
  int g = blockIdx.x*64 + threadIdx.x;
  if (g > NG) return;
  int lo = 0, hi = NN;
  while (lo < hi){
    int mid = (lo + hi) >> 1;
    if (batch[mid] < g) lo = mid + 1; else hi = mid;
  }
  gptr[g] = lo;
}

// ---------------- K1: m = hbf @ W[l]  (MFMA, B^T = WT_bf [f][k]) -> bf16 ----------------
__global__ __launch_bounds__(256) void gemm_m_bf16(
    const ushort* __restrict__ Abf, const ushort* __restrict__ Bt,
    ushort* __restrict__ Mout)
{
  int wv = threadIdx.x >> 6, lane = threadIdx.x & 63;
  int mt = blockIdx.x*4 + wv;
  if (mt >= NN/16) return;
  int m0 = mt*16, mrow = lane & 15, quad = lane >> 4;
  floatx4 acc[8] = {};
  for (int kc = 0; kc < 4; kc++){
    int k0 = kc*32 + quad*8;
    short8 a = load_frag(&Abf[(size_t)(m0 + mrow)*HD + k0]);
    #pragma unroll
    for (int ft = 0; ft < 8; ft++){
      short8 b = load_frag(&Bt[(size_t)(ft*16 + mrow)*HD + k0]);
      acc[ft] = MFMA(a, b, acc[ft]);
    }
  }
  #pragma unroll
  for (int ft = 0; ft < 8; ft++){
    #pragma unroll
    for (int r = 0; r < 4; r++){
      int n = m0 + quad*4 + r;
      Mout[(size_t)n*HD + ft*16 + mrow] = f2bf(acc[ft][r]);
    }
  }
}

// ---------------- K2: aggr[n] = sum_{e: dst=n} m[src]  (bf16 in, bf16 out) ----------------
__global__ __launch_bounds__(256) void aggregate_bf16(
    const uint* __restrict__ m, const int* __restrict__ row_ptr,
    const int* __restrict__ csr_src, uint* __restrict__ aggr)
{
  int nid = blockIdx.x*4 + (threadIdx.x >> 6);
  int lane = threadIdx.x & 63;
  if (nid >= NN) return;
  int s0 = row_ptr[nid], s1 = row_ptr[nid+1];
  float ax = 0.f, ay = 0.f;
  int j = s0;
  for (; j + 1 < s1; j += 2){
    int sA = csr_src[j], sB = csr_src[j+1];
    uint vA = m[(size_t)sA*64 + lane];
    uint vB = m[(size_t)sB*64 + lane];
    ax += __uint_as_float(vA << 16);
    ay += __uint_as_float(vA & 0xFFFF0000u);
    ax += __uint_as_float(vB << 16);
    ay += __uint_as_float(vB & 0xFFFF0000u);
  }
  if (j < s1){
    int s = csr_src[j];
    uint v = m[(size_t)s*64 + lane];
    ax += __uint_as_float(v << 16);
    ay += __uint_as_float(v & 0xFFFF0000u);
  }
  aggr[(size_t)nid*64 + lane] = (uint)f2bf(ax) | ((uint)f2bf(ay) << 16);
}

// ---------------- K3: fused GRU via MFMA ----------------
__global__ __launch_bounds__(256) void gru_mfma(
    const ushort* __restrict__ aggr_bf, const ushort* __restrict__ h_bf,
    const float* __restrict__ h_f32,
    const ushort* __restrict__ wih_bf, const ushort* __restrict__ whh_bf,
    const float* __restrict__ b_ih, const float* __restrict__ b_hh,
    float* __restrict__ hout_f32, ushort* __restrict__ hout_bf)
{
  int wv = threadIdx.x >> 6, lane = threadIdx.x & 63;
  int mrow = lane & 15, quad = lane >> 4;
  int m0 = blockIdx.x * 32;
  bool v1 = (m0 + 16) < NN;
  floatx4 aR[2][2] = {}, aZ[2][2] = {}, aIN[2][2] = {}, aHN[2][2] = {};

  for (int kc = 0; kc < 4; kc++){
    int k0 = kc*32 + quad*8;
    short8 fa[2], fh[2];
    fa[0] = load_frag(&aggr_bf[(size_t)(m0 + mrow)*HD + k0]);
    fh[0] = load_frag(&h_bf  [(size_t)(m0 + mrow)*HD + k0]);
    if (v1){
      fa[1] = load_frag(&aggr_bf[(size_t)(m0 + 16 + mrow)*HD + k0]);
      fh[1] = load_frag(&h_bf  [(size_t)(m0 + 16 + mrow)*HD + k0]);
    } else { fa[1] = zero_frag(); fh[1] = zero_frag(); }
    #pragma unroll
    for (int ftl = 0; ftl < 2; ftl++){
      size_t wo = (size_t)((wv*2 + ftl)*16 + mrow)*HD + k0;
      short8 wir = load_frag(&wih_bf[wo]);
      short8 wiz = load_frag(&wih_bf[128*HD + wo]);
      short8 win = load_frag(&wih_bf[256*HD + wo]);
      short8 whr = load_frag(&whh_bf[wo]);
      short8 whz = load_frag(&whh_bf[128*HD + wo]);
      short8 whn = load_frag(&whh_bf[256*HD + wo]);
      #pragma unroll
      for (int i = 0; i < 2; i++){
        aR[i][ftl]  = MFMA(fa[i], wir, aR[i][ftl]);
        aR[i][ftl]  = MFMA(fh[i], whr, aR[i][ftl]);
        aZ[i][ftl]  = MFMA(fa[i], wiz, aZ[i][ftl]);
        aZ[i][ftl]  = MFMA(fh[i], whz, aZ[i][ftl]);
        aIN[i][ftl] = MFMA(fa[i], win, aIN[i][ftl]);
        aHN[i][ftl] = MFMA(fh[i], whn, aHN[i][ftl]);
      }
    }
  }

  #pragma unroll
  for (int ftl = 0; ftl < 2; ftl++){
    int feat = (wv*2 + ftl)*16 + mrow;
    float bir = b_ih[feat], biz = b_ih[128+feat], bin = b_ih[256+feat];
    float bhr = b_hh[feat], bhz = b_hh[128+feat], bhn = b_hh[256+feat];
    #pragma unroll
    for (int i = 0; i < 2; i++){
      if (i == 1 && !v1) break;
      #pragma unroll
      for (int r = 0; r < 4; r++){
        int node = m0 + i*16 + quad*4 + r;
        float rr = sigmf(aR[i][ftl][r] + bir + bhr);
        float zz = sigmf(aZ[i][ftl][r] + biz + bhz);
        float nn = tanhff(aIN[i][ftl][r] + bin + rr*(aHN[i][ftl][r] + bhn));
        float ho = h_f32[(size_t)node*HD + feat];
        float hv = (1.f - zz)*nn + zz*ho;
        hout_f32[(size_t)node*HD + feat] = hv;
        hout_bf [(size_t)node*HD + feat] = f2bf(hv);
      }
    }
  }
}

// ---------------- local head: relu(hbf @ local_w^T + b) -> fp32 ----------------
__global__ __launch_bounds__(256) void local_gemm_mfma(
    const ushort* __restrict__ hbf, const ushort* __restrict__ lw_bf,
    const float* __restrict__ bias, float* __restrict__ local)
{
  int wv = threadIdx.x >> 6, lane = threadIdx.x & 63;
  int mt = blockIdx.x*4 + wv;
  if (mt >= NN/16) return;
  int m0 = mt*16, mrow = lane & 15, quad = lane >> 4;
  floatx4 acc[8] = {};
  for (int kc = 0; kc < 4; kc++){
    int k0 = kc*32 + quad*8;
    short8 a = load_frag(&hbf[(size_t)(m0 + mrow)*HD + k0]);
    #pragma unroll
    for (int ft = 0; ft < 8; ft++){
      short8 b = load_frag(&lw_bf[(size_t)(ft*16 + mrow)*HD + k0]);
      acc[ft] = MFMA(a, b, acc[ft]);
    }
  }
  #pragma unroll
  for (int ft = 0; ft < 8; ft++){
    float bv = bias[ft*16 + mrow];
    #pragma unroll
    for (int r = 0; r < 4; r++){
      int n = m0 + quad*4 + r;
      local[(size_t)n*HD + ft*16 + mrow] = fmaxf(acc[ft][r] + bv, 0.f);
    }
  }
}

// ---------------- segmented mean-pool (batch sorted, zero atomics) ----------------
__global__ __launch_bounds__(256) void pool_kernel(
    const float* __restrict__ local, const int* __restrict__ gptr,
    float* __restrict__ pooled)
{
  __shared__ float4 red[8][32];
  int g = blockIdx.x;
  int lane = threadIdx.x & 31;
  int st = threadIdx.x >> 5;
  int s0 = gptr[g], s1 = gptr[g+1];
  float4 acc = make_float4(0,0,0,0);
  for (int n = s0 + st; n < s1; n += 8){
    float4 v = *(const float4*)&local[(size_t)n*HD + lane*4];
    acc.x += v.x; acc.y += v.y; acc.z += v.z; acc.w += v.w;
  }
  red[st][lane] = acc;
  __syncthreads();
  if (st == 0){
    float4 s = red[0][lane];
    #pragma unroll
    for (int i=1;i<8;i++){
      float4 v = red[i][lane];
      s.x += v.x; s.y += v.y; s.z += v.z; s.w += v.w;
    }
    float cnt = (float)(s1 - s0);
    if (cnt < 1.0f) cnt = 1.0f;
    float inv = 1.0f / cnt;
    s.x *= inv; s.y *= inv; s.z *= inv; s.w *= inv;
    *(float4*)&pooled[g*HD + lane*4] = s;
  }
}

// ---------------- classifier + log_softmax ----------------
__global__ __launch_bounds__(64) void classifier_kernel(
    const float* __restrict__ pooled,
    const float* __restrict__ gw, const float* __restrict__ gb,
    float* __restrict__ out)
{
  int g = blockIdx.x;
  int lane = threadIdx.x;
  float p0 = pooled[g*HD + lane];
  float p1 = pooled[g*HD + 64 + lane];
  float vals[NC];
  #pragma unroll
  for (int c=0;c<NC;c++){
    float s = p0*gw[c*HD + lane] + p1*gw[c*HD + 64 + lane];
    #pragma unroll
    for (int off=32; off>0; off>>=1) s += __shfl_down(s, off, 64);
    vals[c] = s;
  }
  if (lane == 0){
    float mx = -1e30f;
    #pragma unroll
    for (int c=0;c<NC;c++){ vals[c] += gb[c]; mx = fmaxf(mx, vals[c]); }
    float se = 0.f;
    #pragma unroll
    for (int c=0;c<NC;c++) se += __expf(vals[c] - mx);
    float lse = mx + __logf(se);
    #pragma unroll
    for (int c=0;c<NC;c++) out[g*NC + c] = vals[c] - lse;
  }
}

extern "C" void kernel_launch(void* const* d_in, const int* in_sizes, int n_in,
                              void* d_out, int out_size, void* d_ws, size_t ws_size,
                              hipStream_t stream)
{
  const float* x        = (const float*)d_in[0];
  const int*   ei       = (const int*)  d_in[1];
  const int*   batch    = (const int*)  d_in[2];
  const float* W        = (const float*)d_in[3];
  const float* w_ih     = (const float*)d_in[4];
  const float* w_hh     = (const float*)d_in[5];
  const float* b_ih     = (const float*)d_in[6];
  const float* b_hh     = (const float*)d_in[7];
  const float* local_w  = (const float*)d_in[8];
  const float* local_b  = (const float*)d_in[9];
  const float* global_w = (const float*)d_in[10];
  const float* global_b = (const float*)d_in[11];
  float* out = (float*)d_out;

  // workspace layout (bytes) — total ~81 MB
  char* base = (char*)d_ws;
  float*  h       = (float*)base;                     // 25.6 MB fp32 h master
  char*   R       = base + 25600000;                  // 25.6 MB: m_bf+aggr_bf, reused as local fp32
  ushort* m_bf    = (ushort*)R;                       // 12.8 MB
  ushort* aggr_bf = (ushort*)(R + 12800000);          // 12.8 MB
  float*  local   = (float*)R;                        // 25.6 MB (after GRU layers done)
  ushort* xbf     = (ushort*)(base + 51200000);       // 12.8 MB
  ushort* hbf     = (ushort*)(base + 64000000);       // 12.8 MB
  ushort* wih_bf  = (ushort*)(base + 76800000);       // 96 KB
  ushort* whh_bf  = wih_bf + 49152;
  ushort* WT_bf   = whh_bf + 49152;                   // 128 KB ([l][f][k])
  ushort* lw_bf   = WT_bf + 65536;
  float*  pooled  = (float*)(lw_bf + 16384);          // 128 KB
  int* row_ptr    = (int*)(pooled + 32768);           // NN+1
  int* cursor     = row_ptr + (NN + 1);               // NN
  int* csr_src    = cursor + NN;                      // NE
  int* gptr       = csr_src + NE;                     // NG+1
  int* bsum       = gptr + (NG + 1);                  // 49

  const int* esrc = ei;
  const int* edst = ei + NE;

  hipMemsetAsync(cursor, 0, NN*sizeof(int), stream);
  prep_weights_bf16<<<704, 256, 0, stream>>>(w_ih, w_hh, W, local_w, wih_bf, whh_bf, WT_bf, lw_bf);
  convert_x<<<6250, 256, 0, stream>>>((const float4*)x, (ushort4*)xbf);
  count_deg<<<3125, 256, 0, stream>>>(edst, cursor);
  // hierarchical exclusive scan of degrees -> row_ptr & cursor
  scan_blocks<<<49, 1024, 0, stream>>>(cursor, row_ptr, bsum);
  scan_carry<<<1, 64, 0, stream>>>(bsum, row_ptr);
  scan_add<<<49, 1024, 0, stream>>>(bsum, row_ptr, cursor);
  fill_csr<<<3125, 256, 0, stream>>>(esrc, edst, cursor, csr_src);
  graph_ptr_kernel<<<5, 64, 0, stream>>>(batch, gptr);

  const float*  hin_f = x;
  const ushort* hin_b = xbf;
  for (int l = 0; l < NL; l++){
    gemm_m_bf16<<<782, 256, 0, stream>>>(hin_b, WT_bf + l*16384, m_bf);
    aggregate_bf16<<<12500, 256, 0, stream>>>((const uint*)m_bf, row_ptr, csr_src, (uint*)aggr_bf);
    gru_mfma<<<1563, 256, 0, stream>>>(aggr_bf, hin_b, hin_f, wih_bf, whh_bf, b_ih, b_hh, h, hbf);
    hin_f = h; hin_b = hbf;
  }

  local_gemm_mfma<<<782, 256, 0, stream>>>(hbf, lw_bf, local_b, local);
  pool_kernel<<<NG, 256, 0, stream>>>(local, gptr, pooled);
  classifier_kernel<<<NG, 64, 0, stream>>>(pooled, global_w, global_b, out);
}

// Round 5
// 617.591 us; speedup vs baseline: 2.7862x; 1.2252x over previous
//
#include <hip/hip_runtime.h>

#define NN 50000
#define NE 800000
#define HD 128
#define NL 4
#define NC 10
#define NG 256

typedef __attribute__((ext_vector_type(8))) short short8;    // 8 bf16 = 4 VGPR (MFMA A/B frag)
typedef __attribute__((ext_vector_type(4))) float floatx4;   // MFMA C/D frag

union frg { uint4 u; short8 s; };

__device__ __forceinline__ short8 load_frag(const ushort* p){
  frg f; f.u = *(const uint4*)p; return f.s;
}
__device__ __forceinline__ floatx4 MFMA(short8 a, short8 b, floatx4 c){
  return __builtin_amdgcn_mfma_f32_16x16x32_bf16(a, b, c, 0, 0, 0);
}

__device__ __forceinline__ ushort f2bf(float x){           // RNE fp32->bf16
  unsigned u = __float_as_uint(x);
  return (ushort)((u + 0x7FFFu + ((u >> 16) & 1u)) >> 16);
}
__device__ __forceinline__ float sigmf(float x){ return 1.0f/(1.0f + __expf(-x)); }
__device__ __forceinline__ float tanhff(float x){ return 2.0f/(1.0f + __expf(-2.0f*x)) - 1.0f; }

// ---------------- prep: convert whh / local_w to bf16 ----------------
__global__ __launch_bounds__(256) void prep_weights_bf16(
    const float* __restrict__ w_hh, const float* __restrict__ local_w,
    ushort* __restrict__ whh_bf, ushort* __restrict__ lw_bf)
{
  int idx = blockIdx.x*256 + threadIdx.x;
  if (idx < 49152) whh_bf[idx] = f2bf(w_hh[idx]);
  else if (idx < 65536){ int j = idx - 49152; lw_bf[j] = f2bf(local_w[j]); }
}

// ---------------- Veff[l]^T[o][j] = sum_f W[l][j][f] * wih[o][f]  (fp32 acc -> bf16) ----------------
// Folds the message GEMM into the GRU ih-gates: gi = sumh @ VeffT^T
__global__ __launch_bounds__(256) void veff_kernel(
    const float* __restrict__ W, const float* __restrict__ w_ih,
    ushort* __restrict__ veffT)
{
  int idx = blockIdx.x*256 + threadIdx.x;    // l*49152 + o*128 + j
  if (idx >= 4*49152) return;
  int l = idx / 49152, rem = idx % 49152;
  int o = rem >> 7, j = rem & 127;
  const float4* wr = (const float4*)&W[(size_t)(l*128 + j)*128];
  const float4* ir = (const float4*)&w_ih[(size_t)o*128];
  float acc = 0.f;
  #pragma unroll
  for (int q = 0; q < 32; q++){
    float4 a = wr[q], b = ir[q];
    acc += a.x*b.x + a.y*b.y + a.z*b.z + a.w*b.w;
  }
  veffT[idx] = f2bf(acc);
}

__global__ __launch_bounds__(256) void convert_x(const float4* __restrict__ x, ushort4* __restrict__ xbf)
{
  int i = blockIdx.x*256 + threadIdx.x;
  if (i < NN*HD/4){
    float4 v = x[i];
    ushort4 o; o.x=f2bf(v.x); o.y=f2bf(v.y); o.z=f2bf(v.z); o.w=f2bf(v.w);
    xbf[i] = o;
  }
}

// ---------------- CSR build ----------------
__global__ __launch_bounds__(256) void count_deg(const int* __restrict__ dst, int* deg)
{
  int e = blockIdx.x*256 + threadIdx.x;
  if (e < NE) atomicAdd(&deg[dst[e]], 1);
}

__global__ __launch_bounds__(1024) void scan_blocks(
    const int* __restrict__ deg, int* __restrict__ excl_out, int* __restrict__ bsum)
{
  __shared__ int wsum[16];
  int t = threadIdx.x;
  int gid = blockIdx.x*1024 + t;
  int v = (gid < NN) ? deg[gid] : 0;
  int lane = t & 63, wv = t >> 6;
  int incl = v;
  #pragma unroll
  for (int off=1; off<64; off<<=1){
    int y = __shfl_up(incl, off, 64);
    if (lane >= off) incl += y;
  }
  if (lane == 63) wsum[wv] = incl;
  __syncthreads();
  if (wv == 0){
    int s = (lane < 16) ? wsum[lane] : 0;
    #pragma unroll
    for (int off=1; off<16; off<<=1){
      int y = __shfl_up(s, off, 64);
      if (lane >= off) s += y;
    }
    if (lane < 16) wsum[lane] = s;
  }
  __syncthreads();
  int wpre = (wv > 0) ? wsum[wv-1] : 0;
  if (gid < NN) excl_out[gid] = wpre + incl - v;
  if (t == 1023) bsum[blockIdx.x] = wpre + incl;
}

__global__ __launch_bounds__(64) void scan_carry(int* bsum, int* __restrict__ row_ptr)
{
  int lane = threadIdx.x;
  int v = (lane < 49) ? bsum[lane] : 0;
  int incl = v;
  #pragma unroll
  for (int off=1; off<64; off<<=1){
    int y = __shfl_up(incl, off, 64);
    if (lane >= off) incl += y;
  }
  if (lane < 49) bsum[lane] = incl - v;
  if (lane == 0) row_ptr[NN] = NE;
}

__global__ __launch_bounds__(1024) void scan_add(
    const int* __restrict__ bsum, int* __restrict__ row_ptr, int* __restrict__ cursor)
{
  int gid = blockIdx.x*1024 + threadIdx.x;
  if (gid < NN){
    int v = row_ptr[gid] + bsum[blockIdx.x];
    row_ptr[gid] = v;
    cursor[gid]  = v;
  }
}

__global__ __launch_bounds__(256) void fill_csr(
    const int* __restrict__ src, const int* __restrict__ dst,
    int* cursor, int* __restrict__ csr_src)
{
  int e = blockIdx.x*256 + threadIdx.x;
  if (e < NE){
    int pos = atomicAdd(&cursor[dst[e]], 1);
    csr_src[pos] = src[e];
  }
}

__global__ __launch_bounds__(64) void graph_ptr_kernel(const int* __restrict__ batch, int* __restrict__ gptr)
{
  int g = blockIdx.x*64 + threadIdx.x;
  if (g > NG) return;
  int lo = 0, hi = NN;
  while (lo < hi){
    int mid = (lo + hi) >> 1;
    if (batch[mid] < g) lo = mid + 1; else hi = mid;
  }
  gptr[g] = lo;
}

// ---------------- K2: sumh[n] = sum_{e: dst=n} h[src]  (bf16 in, bf16 out) ----------------
__global__ __launch_bounds__(256) void aggregate_bf16(
    const uint* __restrict__ m, const int* __restrict__ row_ptr,
    const int* __restrict__ csr_src, uint* __restrict__ aggr)
{
  int nid = blockIdx.x*4 + (threadIdx.x >> 6);
  int lane = threadIdx.x & 63;
  if (nid >= NN) return;
  int s0 = row_ptr[nid], s1 = row_ptr[nid+1];
  float ax = 0.f, ay = 0.f;
  int j = s0;
  for (; j + 3 < s1; j += 4){
    int sA = csr_src[j], sB = csr_src[j+1], sC = csr_src[j+2], sD = csr_src[j+3];
    uint vA = m[(size_t)sA*64 + lane];
    uint vB = m[(size_t)sB*64 + lane];
    uint vC = m[(size_t)sC*64 + lane];
    uint vD = m[(size_t)sD*64 + lane];
    ax += __uint_as_float(vA << 16) + __uint_as_float(vB << 16);
    ay += __uint_as_float(vA & 0xFFFF0000u) + __uint_as_float(vB & 0xFFFF0000u);
    ax += __uint_as_float(vC << 16) + __uint_as_float(vD << 16);
    ay += __uint_as_float(vC & 0xFFFF0000u) + __uint_as_float(vD & 0xFFFF0000u);
  }
  for (; j < s1; j++){
    int s = csr_src[j];
    uint v = m[(size_t)s*64 + lane];
    ax += __uint_as_float(v << 16);
    ay += __uint_as_float(v & 0xFFFF0000u);
  }
  aggr[(size_t)nid*64 + lane] = (uint)f2bf(ax) | ((uint)f2bf(ay) << 16);
}

// ---------------- K3: fused GRU via MFMA, LDS-staged inputs ----------------
// block 256 = 4 waves; 32 nodes/block (2 m-tiles); wave wv covers feats [wv*32,wv*32+32)
// ih-gates use sumh @ VeffT (message GEMM folded in); hh-gates use h @ whh^T
// LDS: frag-ordered chunks of 1KB: chunk(arr,tt,kc) -> lane*16B, conflict-free ds_read_b128
__global__ __launch_bounds__(256) void gru_mfma2(
    const ushort* __restrict__ sumh_bf, const ushort* __restrict__ h_bf,
    const float* __restrict__ h_f32,
    const ushort* __restrict__ veffT, const ushort* __restrict__ whh_bf,
    const float* __restrict__ b_ih, const float* __restrict__ b_hh,
    float* __restrict__ hout_f32, ushort* __restrict__ hout_bf)
{
  __shared__ __align__(16) ushort lds_buf[8192];   // 16 KB
  int t = threadIdx.x;
  int wv = t >> 6, lane = t & 63;
  int mrow = lane & 15, quad = lane >> 4;
  int nb = blockIdx.x * 32;

  // stage: 16 chunks (arr{sumh,h} x tt{0,1} x kc{0..3}), wave wv stages chunks wv*4..wv*4+3
  #pragma unroll
  for (int q = 0; q < 4; q++){
    int c = wv*4 + q;                      // c = arr*8 + tt*4 + kc
    int arr = c >> 3, tt = (c >> 2) & 1, kc = c & 3;
    const ushort* srcb = arr ? h_bf : sumh_bf;
    int node = nb + tt*16 + mrow; if (node >= NN) node = NN-1;
    uint4 v = *(const uint4*)&srcb[(size_t)node*HD + kc*32 + quad*8];
    *(uint4*)&lds_buf[c*512 + lane*8] = v;
  }
  __syncthreads();

  floatx4 aR[2][2] = {}, aZ[2][2] = {}, aIN[2][2] = {}, aHN[2][2] = {};

  #pragma unroll
  for (int kc = 0; kc < 4; kc++){
    int k0 = kc*32 + quad*8;
    short8 fa[2], fh[2];
    #pragma unroll
    for (int tt = 0; tt < 2; tt++){
      fa[tt] = load_frag(&lds_buf[((tt<<2) | kc)*512 + lane*8]);
      fh[tt] = load_frag(&lds_buf[((8 | (tt<<2) | kc))*512 + lane*8]);
    }
    #pragma unroll
    for (int ftl = 0; ftl < 2; ftl++){
      size_t wo = (size_t)((wv*2 + ftl)*16 + mrow)*HD + k0;
      short8 vir = load_frag(&veffT[wo]);
      short8 viz = load_frag(&veffT[128*HD + wo]);
      short8 vin = load_frag(&veffT[256*HD + wo]);
      short8 whr = load_frag(&whh_bf[wo]);
      short8 whz = load_frag(&whh_bf[128*HD + wo]);
      short8 whn = load_frag(&whh_bf[256*HD + wo]);
      #pragma unroll
      for (int tt = 0; tt < 2; tt++){
        aR[tt][ftl]  = MFMA(fa[tt], vir, aR[tt][ftl]);
        aR[tt][ftl]  = MFMA(fh[tt], whr, aR[tt][ftl]);
        aZ[tt][ftl]  = MFMA(fa[tt], viz, aZ[tt][ftl]);
        aZ[tt][ftl]  = MFMA(fh[tt], whz, aZ[tt][ftl]);
        aIN[tt][ftl] = MFMA(fa[tt], vin, aIN[tt][ftl]);
        aHN[tt][ftl] = MFMA(fh[tt], whn, aHN[tt][ftl]);
      }
    }
  }

  #pragma unroll
  for (int ftl = 0; ftl < 2; ftl++){
    int feat = (wv*2 + ftl)*16 + mrow;
    float bir = b_ih[feat], biz = b_ih[128+feat], bin = b_ih[256+feat];
    float bhr = b_hh[feat], bhz = b_hh[128+feat], bhn = b_hh[256+feat];
    #pragma unroll
    for (int tt = 0; tt < 2; tt++){
      #pragma unroll
      for (int r = 0; r < 4; r++){
        int node = nb + tt*16 + quad*4 + r;
        if (node >= NN) continue;
        float rr = sigmf(aR[tt][ftl][r] + bir + bhr);
        float zz = sigmf(aZ[tt][ftl][r] + biz + bhz);
        float nn = tanhff(aIN[tt][ftl][r] + bin + rr*(aHN[tt][ftl][r] + bhn));
        float ho = h_f32[(size_t)node*HD + feat];
        float hv = (1.f - zz)*nn + zz*ho;
        hout_f32[(size_t)node*HD + feat] = hv;
        hout_bf [(size_t)node*HD + feat] = f2bf(hv);
      }
    }
  }
}

// ---------------- local head: relu(hbf @ local_w^T + b) -> fp32 ----------------
__global__ __launch_bounds__(256) void local_gemm_mfma(
    const ushort* __restrict__ hbf, const ushort* __restrict__ lw_bf,
    const float* __restrict__ bias, float* __restrict__ local)
{
  int wv = threadIdx.x >> 6, lane = threadIdx.x & 63;
  int mt = blockIdx.x*4 + wv;
  if (mt >= NN/16) return;
  int m0 = mt*16, mrow = lane & 15, quad = lane >> 4;
  floatx4 acc[8] = {};
  for (int kc = 0; kc < 4; kc++){
    int k0 = kc*32 + quad*8;
    short8 a = load_frag(&hbf[(size_t)(m0 + mrow)*HD + k0]);
    #pragma unroll
    for (int ft = 0; ft < 8; ft++){
      short8 b = load_frag(&lw_bf[(size_t)(ft*16 + mrow)*HD + k0]);
      acc[ft] = MFMA(a, b, acc[ft]);
    }
  }
  #pragma unroll
  for (int ft = 0; ft < 8; ft++){
    float bv = bias[ft*16 + mrow];
    #pragma unroll
    for (int r = 0; r < 4; r++){
      int n = m0 + quad*4 + r;
      local[(size_t)n*HD + ft*16 + mrow] = fmaxf(acc[ft][r] + bv, 0.f);
    }
  }
}

// ---------------- segmented mean-pool (batch sorted, zero atomics) ----------------
__global__ __launch_bounds__(256) void pool_kernel(
    const float* __restrict__ local, const int* __restrict__ gptr,
    float* __restrict__ pooled)
{
  __shared__ float4 red[8][32];
  int g = blockIdx.x;
  int lane = threadIdx.x & 31;
  int st = threadIdx.x >> 5;
  int s0 = gptr[g], s1 = gptr[g+1];
  float4 acc = make_float4(0,0,0,0);
  for (int n = s0 + st; n < s1; n += 8){
    float4 v = *(const float4*)&local[(size_t)n*HD + lane*4];
    acc.x += v.x; acc.y += v.y; acc.z += v.z; acc.w += v.w;
  }
  red[st][lane] = acc;
  __syncthreads();
  if (st == 0){
    float4 s = red[0][lane];
    #pragma unroll
    for (int i=1;i<8;i++){
      float4 v = red[i][lane];
      s.x += v.x; s.y += v.y; s.z += v.z; s.w += v.w;
    }
    float cnt = (float)(s1 - s0);
    if (cnt < 1.0f) cnt = 1.0f;
    float inv = 1.0f / cnt;
    s.x *= inv; s.y *= inv; s.z *= inv; s.w *= inv;
    *(float4*)&pooled[g*HD + lane*4] = s;
  }
}

// ---------------- classifier + log_softmax ----------------
__global__ __launch_bounds__(64) void classifier_kernel(
    const float* __restrict__ pooled,
    const float* __restrict__ gw, const float* __restrict__ gb,
    float* __restrict__ out)
{
  int g = blockIdx.x;
  int lane = threadIdx.x;
  float p0 = pooled[g*HD + lane];
  float p1 = pooled[g*HD + 64 + lane];
  float vals[NC];
  #pragma unroll
  for (int c=0;c<NC;c++){
    float s = p0*gw[c*HD + lane] + p1*gw[c*HD + 64 + lane];
    #pragma unroll
    for (int off=32; off>0; off>>=1) s += __shfl_down(s, off, 64);
    vals[c] = s;
  }
  if (lane == 0){
    float mx = -1e30f;
    #pragma unroll
    for (int c=0;c<NC;c++){ vals[c] += gb[c]; mx = fmaxf(mx, vals[c]); }
    float se = 0.f;
    #pragma unroll
    for (int c=0;c<NC;c++) se += __expf(vals[c] - mx);
    float lse = mx + __logf(se);
    #pragma unroll
    for (int c=0;c<NC;c++) out[g*NC + c] = vals[c] - lse;
  }
}

extern "C" void kernel_launch(void* const* d_in, const int* in_sizes, int n_in,
                              void* d_out, int out_size, void* d_ws, size_t ws_size,
                              hipStream_t stream)
{
  const float* x        = (const float*)d_in[0];
  const int*   ei       = (const int*)  d_in[1];
  const int*   batch    = (const int*)  d_in[2];
  const float* W        = (const float*)d_in[3];
  const float* w_ih     = (const float*)d_in[4];
  const float* w_hh     = (const float*)d_in[5];
  const float* b_ih     = (const float*)d_in[6];
  const float* b_hh     = (const float*)d_in[7];
  const float* local_w  = (const float*)d_in[8];
  const float* local_b  = (const float*)d_in[9];
  const float* global_w = (const float*)d_in[10];
  const float* global_b = (const float*)d_in[11];
  float* out = (float*)d_out;

  // workspace layout (~80.6 MB)
  char* base = (char*)d_ws;
  float*  h       = (float*)base;                     // 25.6 MB fp32 h master
  char*   R       = base + 25600000;                  // 25.6 MB multi-use region
  ushort* sumh_bf = (ushort*)R;                       //   12.8 MB (live during layers)
  ushort* veffT   = (ushort*)(R + 12800000);          //   384 KB  (live during layers)
  ushort* whh_bf  = (ushort*)(R + 13193216);          //   96 KB   (live during layers)
  float*  local   = (float*)R;                        //   25.6 MB (after layers; clobbers the above)
  ushort* xbf     = (ushort*)(base + 51200000);       // 12.8 MB
  ushort* hbf     = (ushort*)(base + 64000000);       // 12.8 MB
  ushort* lw_bf   = (ushort*)(base + 76800000);       // 32 KB
  float*  pooled  = (float*)(base + 76832768);        // 128 KB
  int* row_ptr    = (int*)(base + 76963840);          // NN+1
  int* cursor     = row_ptr + (NN + 1);               // NN
  int* csr_src    = cursor + NN;                      // NE
  int* gptr       = csr_src + NE;                     // NG+1
  int* bsum       = gptr + (NG + 1);                  // 49

  const int* esrc = ei;
  const int* edst = ei + NE;

  hipMemsetAsync(cursor, 0, NN*sizeof(int), stream);
  prep_weights_bf16<<<256, 256, 0, stream>>>(w_hh, local_w, whh_bf, lw_bf);
  veff_kernel<<<768, 256, 0, stream>>>(W, w_ih, veffT);
  convert_x<<<6250, 256, 0, stream>>>((const float4*)x, (ushort4*)xbf);
  count_deg<<<3125, 256, 0, stream>>>(edst, cursor);
  scan_blocks<<<49, 1024, 0, stream>>>(cursor, row_ptr, bsum);
  scan_carry<<<1, 64, 0, stream>>>(bsum, row_ptr);
  scan_add<<<49, 1024, 0, stream>>>(bsum, row_ptr, cursor);
  fill_csr<<<3125, 256, 0, stream>>>(esrc, edst, cursor, csr_src);
  graph_ptr_kernel<<<5, 64, 0, stream>>>(batch, gptr);

  const float*  hin_f = x;
  const ushort* hin_b = xbf;
  for (int l = 0; l < NL; l++){
    aggregate_bf16<<<12500, 256, 0, stream>>>((const uint*)hin_b, row_ptr, csr_src, (uint*)sumh_bf);
    gru_mfma2<<<1563, 256, 0, stream>>>(sumh_bf, hin_b, hin_f,
                                        veffT + (size_t)l*49152, whh_bf,
                                        b_ih, b_hh, h, hbf);
    hin_f = h; hin_b = hbf;
  }

  local_gemm_mfma<<<782, 256, 0, stream>>>(hbf, lw_bf, local_b, local);
  pool_kernel<<<NG, 256, 0, stream>>>(local, gptr, pooled);
  classifier_kernel<<<NG, 64, 0, stream>>>(pooled, global_w, global_b, out);
}

// Round 6
// 578.594 us; speedup vs baseline: 2.9740x; 1.0674x over previous
//
#include <hip/hip_runtime.h>

#define NN 50000
#define NE 800000
#define HD 128
#define NL 4
#define NC 10
#define NG 256

typedef __attribute__((ext_vector_type(8))) short short8;    // 8 bf16 = 4 VGPR (MFMA A/B frag)
typedef __attribute__((ext_vector_type(4))) float floatx4;   // MFMA C/D frag

union frg { uint4 u; short8 s; };

__device__ __forceinline__ short8 load_frag(const ushort* p){
  frg f; f.u = *(const uint4*)p; return f.s;
}
__device__ __forceinline__ floatx4 MFMA(short8 a, short8 b, floatx4 c){
  return __builtin_amdgcn_mfma_f32_16x16x32_bf16(a, b, c, 0, 0, 0);
}

__device__ __forceinline__ ushort f2bf(float x){           // RNE fp32->bf16
  unsigned u = __float_as_uint(x);
  return (ushort)((u + 0x7FFFu + ((u >> 16) & 1u)) >> 16);
}
__device__ __forceinline__ float bf2f(ushort b){
  return __uint_as_float(((uint)b) << 16);
}
__device__ __forceinline__ float sigmf(float x){ return 1.0f/(1.0f + __expf(-x)); }
__device__ __forceinline__ float tanhff(float x){ return 2.0f/(1.0f + __expf(-2.0f*x)) - 1.0f; }

// ---------------- prep: convert whh / local_w to bf16 ----------------
__global__ __launch_bounds__(256) void prep_weights_bf16(
    const float* __restrict__ w_hh, const float* __restrict__ local_w,
    ushort* __restrict__ whh_bf, ushort* __restrict__ lw_bf)
{
  int idx = blockIdx.x*256 + threadIdx.x;
  if (idx < 49152) whh_bf[idx] = f2bf(w_hh[idx]);
  else if (idx < 65536){ int j = idx - 49152; lw_bf[j] = f2bf(local_w[j]); }
}

// ---------------- Veff[l]^T[o][j] = sum_f W[l][j][f] * wih[o][f]  (fp32 acc -> bf16) ----------------
__global__ __launch_bounds__(256) void veff_kernel(
    const float* __restrict__ W, const float* __restrict__ w_ih,
    ushort* __restrict__ veffT)
{
  int idx = blockIdx.x*256 + threadIdx.x;    // l*49152 + o*128 + j
  if (idx >= 4*49152) return;
  int l = idx / 49152, rem = idx % 49152;
  int o = rem >> 7, j = rem & 127;
  const float4* wr = (const float4*)&W[(size_t)(l*128 + j)*128];
  const float4* ir = (const float4*)&w_ih[(size_t)o*128];
  float acc = 0.f;
  #pragma unroll
  for (int q = 0; q < 32; q++){
    float4 a = wr[q], b = ir[q];
    acc += a.x*b.x + a.y*b.y + a.z*b.z + a.w*b.w;
  }
  veffT[idx] = f2bf(acc);
}

__global__ __launch_bounds__(256) void convert_x(const float4* __restrict__ x, ushort4* __restrict__ xbf)
{
  int i = blockIdx.x*256 + threadIdx.x;
  if (i < NN*HD/4){
    float4 v = x[i];
    ushort4 o; o.x=f2bf(v.x); o.y=f2bf(v.y); o.z=f2bf(v.z); o.w=f2bf(v.w);
    xbf[i] = o;
  }
}

// ---------------- CSR build ----------------
__global__ __launch_bounds__(256) void count_deg(const int* __restrict__ dst, int* deg)
{
  int e = blockIdx.x*256 + threadIdx.x;
  if (e < NE) atomicAdd(&deg[dst[e]], 1);
}

__global__ __launch_bounds__(1024) void scan_blocks(
    const int* __restrict__ deg, int* __restrict__ excl_out, int* __restrict__ bsum)
{
  __shared__ int wsum[16];
  int t = threadIdx.x;
  int gid = blockIdx.x*1024 + t;
  int v = (gid < NN) ? deg[gid] : 0;
  int lane = t & 63, wv = t >> 6;
  int incl = v;
  #pragma unroll
  for (int off=1; off<64; off<<=1){
    int y = __shfl_up(incl, off, 64);
    if (lane >= off) incl += y;
  }
  if (lane == 63) wsum[wv] = incl;
  __syncthreads();
  if (wv == 0){
    int s = (lane < 16) ? wsum[lane] : 0;
    #pragma unroll
    for (int off=1; off<16; off<<=1){
      int y = __shfl_up(s, off, 64);
      if (lane >= off) s += y;
    }
    if (lane < 16) wsum[lane] = s;
  }
  __syncthreads();
  int wpre = (wv > 0) ? wsum[wv-1] : 0;
  if (gid < NN) excl_out[gid] = wpre + incl - v;
  if (t == 1023) bsum[blockIdx.x] = wpre + incl;
}

__global__ __launch_bounds__(64) void scan_carry(int* bsum, int* __restrict__ row_ptr)
{
  int lane = threadIdx.x;
  int v = (lane < 49) ? bsum[lane] : 0;
  int incl = v;
  #pragma unroll
  for (int off=1; off<64; off<<=1){
    int y = __shfl_up(incl, off, 64);
    if (lane >= off) incl += y;
  }
  if (lane < 49) bsum[lane] = incl - v;
  if (lane == 0) row_ptr[NN] = NE;
}

__global__ __launch_bounds__(1024) void scan_add(
    const int* __restrict__ bsum, int* __restrict__ row_ptr, int* __restrict__ cursor)
{
  int gid = blockIdx.x*1024 + threadIdx.x;
  if (gid < NN){
    int v = row_ptr[gid] + bsum[blockIdx.x];
    row_ptr[gid] = v;
    cursor[gid]  = v;
  }
}

__global__ __launch_bounds__(256) void fill_csr(
    const int* __restrict__ src, const int* __restrict__ dst,
    int* cursor, int* __restrict__ csr_src)
{
  int e = blockIdx.x*256 + threadIdx.x;
  if (e < NE){
    int pos = atomicAdd(&cursor[dst[e]], 1);
    csr_src[pos] = src[e];
  }
}

__global__ __launch_bounds__(64) void graph_ptr_kernel(const int* __restrict__ batch, int* __restrict__ gptr)
{
  int g = blockIdx.x*64 + threadIdx.x;
  if (g > NG) return;
  int lo = 0, hi = NN;
  while (lo < hi){
    int mid = (lo + hi) >> 1;
    if (batch[mid] < g) lo = mid + 1; else hi = mid;
  }
  gptr[g] = lo;
}

// ---------------- K2: sumh[n] = sum_{e: dst=n} h[src]  (bf16 in, bf16 out) ----------------
__global__ __launch_bounds__(256) void aggregate_bf16(
    const uint* __restrict__ m, const int* __restrict__ row_ptr,
    const int* __restrict__ csr_src, uint* __restrict__ aggr)
{
  int nid = blockIdx.x*4 + (threadIdx.x >> 6);
  int lane = threadIdx.x & 63;
  if (nid >= NN) return;
  int s0 = row_ptr[nid], s1 = row_ptr[nid+1];
  float ax = 0.f, ay = 0.f;
  int j = s0;
  for (; j + 3 < s1; j += 4){
    int sA = csr_src[j], sB = csr_src[j+1], sC = csr_src[j+2], sD = csr_src[j+3];
    uint vA = m[(size_t)sA*64 + lane];
    uint vB = m[(size_t)sB*64 + lane];
    uint vC = m[(size_t)sC*64 + lane];
    uint vD = m[(size_t)sD*64 + lane];
    ax += __uint_as_float(vA << 16) + __uint_as_float(vB << 16);
    ay += __uint_as_float(vA & 0xFFFF0000u) + __uint_as_float(vB & 0xFFFF0000u);
    ax += __uint_as_float(vC << 16) + __uint_as_float(vD << 16);
    ay += __uint_as_float(vC & 0xFFFF0000u) + __uint_as_float(vD & 0xFFFF0000u);
  }
  for (; j < s1; j++){
    int s = csr_src[j];
    uint v = m[(size_t)s*64 + lane];
    ax += __uint_as_float(v << 16);
    ay += __uint_as_float(v & 0xFFFF0000u);
  }
  aggr[(size_t)nid*64 + lane] = (uint)f2bf(ax) | ((uint)f2bf(ay) << 16);
}

// ---------------- K3: fused GRU via MFMA; pure-bf16 h; LDS-transposed coalesced output ----------------
// block 256 = 4 waves; 32 nodes/block; wave wv covers feats [wv*32,wv*32+32)
// ih-gates: sumh @ VeffT (message GEMM folded in); hh-gates: h @ whh^T
// h update is IN-PLACE on h_bf (each block touches only its own 32 rows).
__global__ __launch_bounds__(256) void gru_mfma3(
    const ushort* __restrict__ sumh_bf, ushort* __restrict__ h_bf_out,
    const ushort* __restrict__ h_bf_in,
    const ushort* __restrict__ veffT, const ushort* __restrict__ whh_bf,
    const float* __restrict__ b_ih, const float* __restrict__ b_hh)
{
  __shared__ __align__(16) ushort lds_in[8192];        // 16 KB frag-ordered inputs
  __shared__ __align__(16) ushort lds_out[32*136];     // 8.5 KB hv bf16, stride 136 (pad)
  int t = threadIdx.x;
  int wv = t >> 6, lane = t & 63;
  int mrow = lane & 15, quad = lane >> 4;
  int nb = blockIdx.x * 32;

  // stage: 16 chunks (arr{sumh,h} x tt{0,1} x kc{0..3}); wave wv stages chunks wv*4..wv*4+3
  #pragma unroll
  for (int q = 0; q < 4; q++){
    int c = wv*4 + q;                      // c = arr*8 + tt*4 + kc
    int arr = c >> 3, tt = (c >> 2) & 1, kc = c & 3;
    const ushort* srcb = arr ? h_bf_in : sumh_bf;
    int node = nb + tt*16 + mrow; if (node >= NN) node = NN-1;
    uint4 v = *(const uint4*)&srcb[(size_t)node*HD + kc*32 + quad*8];
    *(uint4*)&lds_in[c*512 + lane*8] = v;
  }
  __syncthreads();

  floatx4 aR[2][2] = {}, aZ[2][2] = {}, aIN[2][2] = {}, aHN[2][2] = {};

  #pragma unroll
  for (int kc = 0; kc < 4; kc++){
    int k0 = kc*32 + quad*8;
    short8 fa[2], fh[2];
    #pragma unroll
    for (int tt = 0; tt < 2; tt++){
      fa[tt] = load_frag(&lds_in[((tt<<2) | kc)*512 + lane*8]);
      fh[tt] = load_frag(&lds_in[((8 | (tt<<2) | kc))*512 + lane*8]);
    }
    #pragma unroll
    for (int ftl = 0; ftl < 2; ftl++){
      size_t wo = (size_t)((wv*2 + ftl)*16 + mrow)*HD + k0;
      short8 vir = load_frag(&veffT[wo]);
      short8 viz = load_frag(&veffT[128*HD + wo]);
      short8 vin = load_frag(&veffT[256*HD + wo]);
      short8 whr = load_frag(&whh_bf[wo]);
      short8 whz = load_frag(&whh_bf[128*HD + wo]);
      short8 whn = load_frag(&whh_bf[256*HD + wo]);
      #pragma unroll
      for (int tt = 0; tt < 2; tt++){
        aR[tt][ftl]  = MFMA(fa[tt], vir, aR[tt][ftl]);
        aR[tt][ftl]  = MFMA(fh[tt], whr, aR[tt][ftl]);
        aZ[tt][ftl]  = MFMA(fa[tt], viz, aZ[tt][ftl]);
        aZ[tt][ftl]  = MFMA(fh[tt], whz, aZ[tt][ftl]);
        aIN[tt][ftl] = MFMA(fa[tt], vin, aIN[tt][ftl]);
        aHN[tt][ftl] = MFMA(fh[tt], whn, aHN[tt][ftl]);
      }
    }
  }

  // epilogue: gates in fp32; ho from staged LDS h tile; hv -> lds_out (bf16)
  #pragma unroll
  for (int ftl = 0; ftl < 2; ftl++){
    int feat = wv*32 + ftl*16 + mrow;
    float bir = b_ih[feat], biz = b_ih[128+feat], bin = b_ih[256+feat];
    float bhr = b_hh[feat], bhz = b_hh[128+feat], bhn = b_hh[256+feat];
    int kw = ftl*16 + mrow;                      // k-position within wave's 32-feat span
    int qq = kw >> 3, jj = kw & 7;
    #pragma unroll
    for (int tt = 0; tt < 2; tt++){
      int cho = (8 | (tt<<2) | wv)*512;          // h chunk, kc = wv
      #pragma unroll
      for (int r = 0; r < 4; r++){
        int nrow = quad*4 + r;
        float rr = sigmf(aR[tt][ftl][r] + bir + bhr);
        float zz = sigmf(aZ[tt][ftl][r] + biz + bhz);
        float nn = tanhff(aIN[tt][ftl][r] + bin + rr*(aHN[tt][ftl][r] + bhn));
        float ho = bf2f(lds_in[cho + (qq*16 + nrow)*8 + jj]);
        float hv = (1.f - zz)*nn + zz*ho;
        lds_out[(tt*16 + nrow)*136 + feat] = f2bf(hv);
      }
    }
  }
  __syncthreads();

  // coalesced write-back: 512 chunks of 8 ushorts (16 B); wave covers 1 KB contiguous
  #pragma unroll
  for (int p = 0; p < 2; p++){
    int chunk = p*256 + t;
    int node = chunk >> 4, f = (chunk & 15)*8;
    int ng = nb + node;
    if (ng < NN){
      uint4 v = *(const uint4*)&lds_out[node*136 + f];
      *(uint4*)&h_bf_out[(size_t)ng*HD + f] = v;
    }
  }
}

// ---------------- local head: relu(hbf @ local_w^T + b) -> fp32 ----------------
__global__ __launch_bounds__(256) void local_gemm_mfma(
    const ushort* __restrict__ hbf, const ushort* __restrict__ lw_bf,
    const float* __restrict__ bias, float* __restrict__ local)
{
  int wv = threadIdx.x >> 6, lane = threadIdx.x & 63;
  int mt = blockIdx.x*4 + wv;
  if (mt >= NN/16) return;
  int m0 = mt*16, mrow = lane & 15, quad = lane >> 4;
  floatx4 acc[8] = {};
  for (int kc = 0; kc < 4; kc++){
    int k0 = kc*32 + quad*8;
    short8 a = load_frag(&hbf[(size_t)(m0 + mrow)*HD + k0]);
    #pragma unroll
    for (int ft = 0; ft < 8; ft++){
      short8 b = load_frag(&lw_bf[(size_t)(ft*16 + mrow)*HD + k0]);
      acc[ft] = MFMA(a, b, acc[ft]);
    }
  }
  #pragma unroll
  for (int ft = 0; ft < 8; ft++){
    float bv = bias[ft*16 + mrow];
    #pragma unroll
    for (int r = 0; r < 4; r++){
      int n = m0 + quad*4 + r;
      local[(size_t)n*HD + ft*16 + mrow] = fmaxf(acc[ft][r] + bv, 0.f);
    }
  }
}

// ---------------- segmented mean-pool (batch sorted, zero atomics) ----------------
__global__ __launch_bounds__(256) void pool_kernel(
    const float* __restrict__ local, const int* __restrict__ gptr,
    float* __restrict__ pooled)
{
  __shared__ float4 red[8][32];
  int g = blockIdx.x;
  int lane = threadIdx.x & 31;
  int st = threadIdx.x >> 5;
  int s0 = gptr[g], s1 = gptr[g+1];
  float4 acc = make_float4(0,0,0,0);
  for (int n = s0 + st; n < s1; n += 8){
    float4 v = *(const float4*)&local[(size_t)n*HD + lane*4];
    acc.x += v.x; acc.y += v.y; acc.z += v.z; acc.w += v.w;
  }
  red[st][lane] = acc;
  __syncthreads();
  if (st == 0){
    float4 s = red[0][lane];
    #pragma unroll
    for (int i=1;i<8;i++){
      float4 v = red[i][lane];
      s.x += v.x; s.y += v.y; s.z += v.z; s.w += v.w;
    }
    float cnt = (float)(s1 - s0);
    if (cnt < 1.0f) cnt = 1.0f;
    float inv = 1.0f / cnt;
    s.x *= inv; s.y *= inv; s.z *= inv; s.w *= inv;
    *(float4*)&pooled[g*HD + lane*4] = s;
  }
}

// ---------------- classifier + log_softmax ----------------
__global__ __launch_bounds__(64) void classifier_kernel(
    const float* __restrict__ pooled,
    const float* __restrict__ gw, const float* __restrict__ gb,
    float* __restrict__ out)
{
  int g = blockIdx.x;
  int lane = threadIdx.x;
  float p0 = pooled[g*HD + lane];
  float p1 = pooled[g*HD + 64 + lane];
  float vals[NC];
  #pragma unroll
  for (int c=0;c<NC;c++){
    float s = p0*gw[c*HD + lane] + p1*gw[c*HD + 64 + lane];
    #pragma unroll
    for (int off=32; off>0; off>>=1) s += __shfl_down(s, off, 64);
    vals[c] = s;
  }
  if (lane == 0){
    float mx = -1e30f;
    #pragma unroll
    for (int c=0;c<NC;c++){ vals[c] += gb[c]; mx = fmaxf(mx, vals[c]); }
    float se = 0.f;
    #pragma unroll
    for (int c=0;c<NC;c++) se += __expf(vals[c] - mx);
    float lse = mx + __logf(se);
    #pragma unroll
    for (int c=0;c<NC;c++) out[g*NC + c] = vals[c] - lse;
  }
}

extern "C" void kernel_launch(void* const* d_in, const int* in_sizes, int n_in,
                              void* d_out, int out_size, void* d_ws, size_t ws_size,
                              hipStream_t stream)
{
  const float* x        = (const float*)d_in[0];
  const int*   ei       = (const int*)  d_in[1];
  const int*   batch    = (const int*)  d_in[2];
  const float* W        = (const float*)d_in[3];
  const float* w_ih     = (const float*)d_in[4];
  const float* w_hh     = (const float*)d_in[5];
  const float* b_ih     = (const float*)d_in[6];
  const float* b_hh     = (const float*)d_in[7];
  const float* local_w  = (const float*)d_in[8];
  const float* local_b  = (const float*)d_in[9];
  const float* global_w = (const float*)d_in[10];
  const float* global_b = (const float*)d_in[11];
  float* out = (float*)d_out;

  // workspace layout (offsets kept from round 5; fp32 h region now unused)
  char* base = (char*)d_ws;
  char*   R       = base + 25600000;                  // 25.6 MB multi-use region
  ushort* sumh_bf = (ushort*)R;                       //   12.8 MB (live during layers)
  ushort* veffT   = (ushort*)(R + 12800000);          //   384 KB  (live during layers)
  ushort* whh_bf  = (ushort*)(R + 13193216);          //   96 KB   (live during layers)
  float*  local   = (float*)R;                        //   25.6 MB (after layers; clobbers the above)
  ushort* xbf     = (ushort*)(base + 51200000);       // 12.8 MB
  ushort* hbf     = (ushort*)(base + 64000000);       // 12.8 MB
  ushort* lw_bf   = (ushort*)(base + 76800000);       // 32 KB
  float*  pooled  = (float*)(base + 76832768);        // 128 KB
  int* row_ptr    = (int*)(base + 76963840);          // NN+1
  int* cursor     = row_ptr + (NN + 1);               // NN
  int* csr_src    = cursor + NN;                      // NE
  int* gptr       = csr_src + NE;                     // NG+1
  int* bsum       = gptr + (NG + 1);                  // 49

  const int* esrc = ei;
  const int* edst = ei + NE;

  hipMemsetAsync(cursor, 0, NN*sizeof(int), stream);
  prep_weights_bf16<<<256, 256, 0, stream>>>(w_hh, local_w, whh_bf, lw_bf);
  veff_kernel<<<768, 256, 0, stream>>>(W, w_ih, veffT);
  convert_x<<<6250, 256, 0, stream>>>((const float4*)x, (ushort4*)xbf);
  count_deg<<<3125, 256, 0, stream>>>(edst, cursor);
  scan_blocks<<<49, 1024, 0, stream>>>(cursor, row_ptr, bsum);
  scan_carry<<<1, 64, 0, stream>>>(bsum, row_ptr);
  scan_add<<<49, 1024, 0, stream>>>(bsum, row_ptr, cursor);
  fill_csr<<<3125, 256, 0, stream>>>(esrc, edst, cursor, csr_src);
  graph_ptr_kernel<<<5, 64, 0, stream>>>(batch, gptr);

  const ushort* hin_b = xbf;
  for (int l = 0; l < NL; l++){
    aggregate_bf16<<<12500, 256, 0, stream>>>((const uint*)hin_b, row_ptr, csr_src, (uint*)sumh_bf);
    // layer 0: read xbf, write hbf; layers 1+: in-place on hbf (blocks touch only own rows)
    gru_mfma3<<<1563, 256, 0, stream>>>(sumh_bf, hbf, hin_b,
                                        veffT + (size_t)l*49152, whh_bf, b_ih, b_hh);
    hin_b = hbf;
  }

  local_gemm_mfma<<<782, 256, 0, stream>>>(hbf, lw_bf, local_b, local);
  pool_kernel<<<NG, 256, 0, stream>>>(local, gptr, pooled);
  classifier_kernel<<<NG, 64, 0, stream>>>(pooled, global_w, global_b, out);
}

// Round 7
// 551.115 us; speedup vs baseline: 3.1223x; 1.0499x over previous
//
#include <hip/hip_runtime.h>

#define NN 50000
#define NE 800000
#define HD 128
#define NL 4
#define NC 10
#define NG 256

typedef __attribute__((ext_vector_type(8))) short short8;    // 8 bf16 = 4 VGPR (MFMA A/B frag)
typedef __attribute__((ext_vector_type(4))) float floatx4;   // MFMA C/D frag

union frg { uint4 u; short8 s; };

__device__ __forceinline__ short8 load_frag(const ushort* p){
  frg f; f.u = *(const uint4*)p; return f.s;
}
__device__ __forceinline__ floatx4 MFMA(short8 a, short8 b, floatx4 c){
  return __builtin_amdgcn_mfma_f32_16x16x32_bf16(a, b, c, 0, 0, 0);
}

__device__ __forceinline__ ushort f2bf(float x){           // RNE fp32->bf16
  unsigned u = __float_as_uint(x);
  return (ushort)((u + 0x7FFFu + ((u >> 16) & 1u)) >> 16);
}
__device__ __forceinline__ float bf2f(ushort b){
  return __uint_as_float(((uint)b) << 16);
}
__device__ __forceinline__ float sigmf(float x){ return 1.0f/(1.0f + __expf(-x)); }
__device__ __forceinline__ float tanhff(float x){ return 2.0f/(1.0f + __expf(-2.0f*x)) - 1.0f; }

// ---------------- prep: convert whh / local_w to bf16; fold biases ----------------
__global__ __launch_bounds__(256) void prep_weights_bf16(
    const float* __restrict__ w_hh, const float* __restrict__ local_w,
    const float* __restrict__ b_ih, const float* __restrict__ b_hh,
    ushort* __restrict__ whh_bf, ushort* __restrict__ lw_bf,
    float* __restrict__ bs)
{
  int idx = blockIdx.x*256 + threadIdx.x;
  if (idx < 49152) whh_bf[idx] = f2bf(w_hh[idx]);
  else if (idx < 65536){ int j = idx - 49152; lw_bf[j] = f2bf(local_w[j]); }
  else if (idx < 66048){
    int j = idx - 65536;       // 0..511: br(128), bz(128), bin(128), bhn(128)
    if (j < 256)      bs[j] = b_ih[j] + b_hh[j];
    else if (j < 384) bs[j] = b_ih[j];          // bin = b_ih[256+f] at j=256+f
    else              bs[j] = b_hh[j - 128];    // bhn = b_hh[256+f] at j=384+f
  }
}

// ---------------- Veff[l]^T[o][j] = sum_f W[l][j][f] * wih[o][f]  (fp32 acc -> bf16) ----------------
__global__ __launch_bounds__(256) void veff_kernel(
    const float* __restrict__ W, const float* __restrict__ w_ih,
    ushort* __restrict__ veffT)
{
  int idx = blockIdx.x*256 + threadIdx.x;    // l*49152 + o*128 + j
  if (idx >= 4*49152) return;
  int l = idx / 49152, rem = idx % 49152;
  int o = rem >> 7, j = rem & 127;
  const float4* wr = (const float4*)&W[(size_t)(l*128 + j)*128];
  const float4* ir = (const float4*)&w_ih[(size_t)o*128];
  float acc = 0.f;
  #pragma unroll
  for (int q = 0; q < 32; q++){
    float4 a = wr[q], b = ir[q];
    acc += a.x*b.x + a.y*b.y + a.z*b.z + a.w*b.w;
  }
  veffT[idx] = f2bf(acc);
}

__global__ __launch_bounds__(256) void convert_x(const float4* __restrict__ x, ushort4* __restrict__ xbf)
{
  int i = blockIdx.x*256 + threadIdx.x;
  if (i < NN*HD/4){
    float4 v = x[i];
    ushort4 o; o.x=f2bf(v.x); o.y=f2bf(v.y); o.z=f2bf(v.z); o.w=f2bf(v.w);
    xbf[i] = o;
  }
}

// ---------------- CSR build ----------------
__global__ __launch_bounds__(256) void count_deg(const int* __restrict__ dst, int* deg)
{
  int e = blockIdx.x*256 + threadIdx.x;
  if (e < NE) atomicAdd(&deg[dst[e]], 1);
}

__global__ __launch_bounds__(1024) void scan_blocks(
    const int* __restrict__ deg, int* __restrict__ excl_out, int* __restrict__ bsum)
{
  __shared__ int wsum[16];
  int t = threadIdx.x;
  int gid = blockIdx.x*1024 + t;
  int v = (gid < NN) ? deg[gid] : 0;
  int lane = t & 63, wv = t >> 6;
  int incl = v;
  #pragma unroll
  for (int off=1; off<64; off<<=1){
    int y = __shfl_up(incl, off, 64);
    if (lane >= off) incl += y;
  }
  if (lane == 63) wsum[wv] = incl;
  __syncthreads();
  if (wv == 0){
    int s = (lane < 16) ? wsum[lane] : 0;
    #pragma unroll
    for (int off=1; off<16; off<<=1){
      int y = __shfl_up(s, off, 64);
      if (lane >= off) s += y;
    }
    if (lane < 16) wsum[lane] = s;
  }
  __syncthreads();
  int wpre = (wv > 0) ? wsum[wv-1] : 0;
  if (gid < NN) excl_out[gid] = wpre + incl - v;
  if (t == 1023) bsum[blockIdx.x] = wpre + incl;
}

__global__ __launch_bounds__(64) void scan_carry(int* bsum, int* __restrict__ row_ptr)
{
  int lane = threadIdx.x;
  int v = (lane < 49) ? bsum[lane] : 0;
  int incl = v;
  #pragma unroll
  for (int off=1; off<64; off<<=1){
    int y = __shfl_up(incl, off, 64);
    if (lane >= off) incl += y;
  }
  if (lane < 49) bsum[lane] = incl - v;
  if (lane == 0) row_ptr[NN] = NE;
}

__global__ __launch_bounds__(1024) void scan_add(
    const int* __restrict__ bsum, int* __restrict__ row_ptr, int* __restrict__ cursor)
{
  int gid = blockIdx.x*1024 + threadIdx.x;
  if (gid < NN){
    int v = row_ptr[gid] + bsum[blockIdx.x];
    row_ptr[gid] = v;
    cursor[gid]  = v;
  }
}

__global__ __launch_bounds__(256) void fill_csr(
    const int* __restrict__ src, const int* __restrict__ dst,
    int* cursor, int* __restrict__ csr_src)
{
  int e = blockIdx.x*256 + threadIdx.x;
  if (e < NE){
    int pos = atomicAdd(&cursor[dst[e]], 1);
    csr_src[pos] = src[e];
  }
}

__global__ __launch_bounds__(64) void graph_ptr_kernel(const int* __restrict__ batch, int* __restrict__ gptr)
{
  int g = blockIdx.x*64 + threadIdx.x;
  if (g > NG) return;
  int lo = 0, hi = NN;
  while (lo < hi){
    int mid = (lo + hi) >> 1;
    if (batch[mid] < g) lo = mid + 1; else hi = mid;
  }
  gptr[g] = lo;
}

// ---------------- K2: sumh[n] = sum_{e: dst=n} h[src]  (bf16 in, bf16 out) ----------------
__global__ __launch_bounds__(256) void aggregate_bf16(
    const uint* __restrict__ m, const int* __restrict__ row_ptr,
    const int* __restrict__ csr_src, uint* __restrict__ aggr)
{
  int nid = blockIdx.x*4 + (threadIdx.x >> 6);
  int lane = threadIdx.x & 63;
  if (nid >= NN) return;
  int s0 = row_ptr[nid], s1 = row_ptr[nid+1];
  float ax = 0.f, ay = 0.f;
  int j = s0;
  for (; j + 3 < s1; j += 4){
    int sA = csr_src[j], sB = csr_src[j+1], sC = csr_src[j+2], sD = csr_src[j+3];
    uint vA = m[(size_t)sA*64 + lane];
    uint vB = m[(size_t)sB*64 + lane];
    uint vC = m[(size_t)sC*64 + lane];
    uint vD = m[(size_t)sD*64 + lane];
    ax += __uint_as_float(vA << 16) + __uint_as_float(vB << 16);
    ay += __uint_as_float(vA & 0xFFFF0000u) + __uint_as_float(vB & 0xFFFF0000u);
    ax += __uint_as_float(vC << 16) + __uint_as_float(vD << 16);
    ay += __uint_as_float(vC & 0xFFFF0000u) + __uint_as_float(vD & 0xFFFF0000u);
  }
  for (; j < s1; j++){
    int s = csr_src[j];
    uint v = m[(size_t)s*64 + lane];
    ax += __uint_as_float(v << 16);
    ay += __uint_as_float(v & 0xFFFF0000u);
  }
  aggr[(size_t)nid*64 + lane] = (uint)f2bf(ax) | ((uint)f2bf(ay) << 16);
}

// ---------------- K3: fused GRU via MFMA; 64 nodes/block, 4x weight reuse ----------------
// block 256 = 4 waves; wave wv covers feats [wv*32,wv*32+32) for ALL 64 nodes (4 m-tiles).
// ih-gates: sumh @ VeffT (message GEMM folded in); hh-gates: h @ whh^T.
// In-place h_bf update is safe: each block only touches its own 64 rows.
__global__ __launch_bounds__(256, 2) void gru_mfma4(
    const ushort* __restrict__ sumh_bf, ushort* __restrict__ h_bf_out,
    const ushort* __restrict__ h_bf_in,
    const ushort* __restrict__ veffT, const ushort* __restrict__ whh_bf,
    const float* __restrict__ bs)
{
  __shared__ __align__(16) ushort lds_in[16384];       // 32 KB: 32 chunks of 1 KB
  __shared__ __align__(16) ushort lds_out[64*136];     // 17 KB hv bf16, stride 136 (16B-aligned rows)
  int t = threadIdx.x;
  int wv = t >> 6, lane = t & 63;
  int mrow = lane & 15, quad = lane >> 4;
  int nb = blockIdx.x * 64;

  // stage: 32 chunks (arr{sumh,h}x16 + tt{0..3}x4 + kc{0..3}); wave wv stages chunks wv*8..wv*8+7
  #pragma unroll
  for (int q = 0; q < 8; q++){
    int c = wv*8 + q;                      // c = arr*16 + tt*4 + kc
    int arr = c >> 4, tt = (c >> 2) & 3, kc = c & 3;
    const ushort* srcb = arr ? h_bf_in : sumh_bf;
    int node = nb + tt*16 + mrow; if (node >= NN) node = NN-1;
    uint4 v = *(const uint4*)&srcb[(size_t)node*HD + kc*32 + quad*8];
    *(uint4*)&lds_in[c*512 + lane*8] = v;
  }
  __syncthreads();

  floatx4 aR[4][2] = {}, aZ[4][2] = {}, aIN[4][2] = {}, aHN[4][2] = {};

  #pragma unroll
  for (int kc = 0; kc < 4; kc++){
    int k0 = kc*32 + quad*8;
    short8 fa[4], fh[4];
    #pragma unroll
    for (int tt = 0; tt < 4; tt++){
      fa[tt] = load_frag(&lds_in[((tt<<2) | kc)*512 + lane*8]);
      fh[tt] = load_frag(&lds_in[(16 | (tt<<2) | kc)*512 + lane*8]);
    }
    #pragma unroll
    for (int ftl = 0; ftl < 2; ftl++){
      size_t wo = (size_t)((wv*2 + ftl)*16 + mrow)*HD + k0;
      short8 vir = load_frag(&veffT[wo]);
      short8 viz = load_frag(&veffT[128*HD + wo]);
      short8 vin = load_frag(&veffT[256*HD + wo]);
      short8 whr = load_frag(&whh_bf[wo]);
      short8 whz = load_frag(&whh_bf[128*HD + wo]);
      short8 whn = load_frag(&whh_bf[256*HD + wo]);
      #pragma unroll
      for (int tt = 0; tt < 4; tt++){
        aR[tt][ftl]  = MFMA(fa[tt], vir, aR[tt][ftl]);
        aR[tt][ftl]  = MFMA(fh[tt], whr, aR[tt][ftl]);
        aZ[tt][ftl]  = MFMA(fa[tt], viz, aZ[tt][ftl]);
        aZ[tt][ftl]  = MFMA(fh[tt], whz, aZ[tt][ftl]);
        aIN[tt][ftl] = MFMA(fa[tt], vin, aIN[tt][ftl]);
        aHN[tt][ftl] = MFMA(fh[tt], whn, aHN[tt][ftl]);
      }
    }
  }

  // epilogue: gates fp32; ho from staged LDS h tile; hv -> lds_out bf16
  #pragma unroll
  for (int ftl = 0; ftl < 2; ftl++){
    int feat = wv*32 + ftl*16 + mrow;
    float br  = bs[feat], bz = bs[128+feat], bin = bs[256+feat], bhn = bs[384+feat];
    int kw = ftl*16 + mrow;                      // k-position within wave's 32-feat span
    int qq = kw >> 3, jj = kw & 7;
    #pragma unroll
    for (int tt = 0; tt < 4; tt++){
      int cho = (16 | (tt<<2) | wv)*512;         // h chunk, kc = wv
      #pragma unroll
      for (int r = 0; r < 4; r++){
        int nrow = quad*4 + r;
        float rr = sigmf(aR[tt][ftl][r] + br);
        float zz = sigmf(aZ[tt][ftl][r] + bz);
        float nn = tanhff(aIN[tt][ftl][r] + bin + rr*(aHN[tt][ftl][r] + bhn));
        float ho = bf2f(lds_in[cho + (qq*16 + nrow)*8 + jj]);
        float hv = (1.f - zz)*nn + zz*ho;
        lds_out[(tt*16 + nrow)*136 + feat] = f2bf(hv);
      }
    }
  }
  __syncthreads();

  // coalesced write-back: 1024 chunks of 8 ushorts (16 B)
  #pragma unroll
  for (int p = 0; p < 4; p++){
    int chunk = p*256 + t;
    int node = chunk >> 4, f = (chunk & 15)*8;
    int ng = nb + node;
    if (ng < NN){
      uint4 v = *(const uint4*)&lds_out[node*136 + f];
      *(uint4*)&h_bf_out[(size_t)ng*HD + f] = v;
    }
  }
}

// ---------------- local head: relu(hbf @ local_w^T + b) -> fp32 ----------------
__global__ __launch_bounds__(256) void local_gemm_mfma(
    const ushort* __restrict__ hbf, const ushort* __restrict__ lw_bf,
    const float* __restrict__ bias, float* __restrict__ local)
{
  int wv = threadIdx.x >> 6, lane = threadIdx.x & 63;
  int mt = blockIdx.x*4 + wv;
  if (mt >= NN/16) return;
  int m0 = mt*16, mrow = lane & 15, quad = lane >> 4;
  floatx4 acc[8] = {};
  for (int kc = 0; kc < 4; kc++){
    int k0 = kc*32 + quad*8;
    short8 a = load_frag(&hbf[(size_t)(m0 + mrow)*HD + k0]);
    #pragma unroll
    for (int ft = 0; ft < 8; ft++){
      short8 b = load_frag(&lw_bf[(size_t)(ft*16 + mrow)*HD + k0]);
      acc[ft] = MFMA(a, b, acc[ft]);
    }
  }
  #pragma unroll
  for (int ft = 0; ft < 8; ft++){
    float bv = bias[ft*16 + mrow];
    #pragma unroll
    for (int r = 0; r < 4; r++){
      int n = m0 + quad*4 + r;
      local[(size_t)n*HD + ft*16 + mrow] = fmaxf(acc[ft][r] + bv, 0.f);
    }
  }
}

// ---------------- segmented mean-pool (batch sorted, zero atomics) ----------------
__global__ __launch_bounds__(256) void pool_kernel(
    const float* __restrict__ local, const int* __restrict__ gptr,
    float* __restrict__ pooled)
{
  __shared__ float4 red[8][32];
  int g = blockIdx.x;
  int lane = threadIdx.x & 31;
  int st = threadIdx.x >> 5;
  int s0 = gptr[g], s1 = gptr[g+1];
  float4 acc = make_float4(0,0,0,0);
  for (int n = s0 + st; n < s1; n += 8){
    float4 v = *(const float4*)&local[(size_t)n*HD + lane*4];
    acc.x += v.x; acc.y += v.y; acc.z += v.z; acc.w += v.w;
  }
  red[st][lane] = acc;
  __syncthreads();
  if (st == 0){
    float4 s = red[0][lane];
    #pragma unroll
    for (int i=1;i<8;i++){
      float4 v = red[i][lane];
      s.x += v.x; s.y += v.y; s.z += v.z; s.w += v.w;
    }
    float cnt = (float)(s1 - s0);
    if (cnt < 1.0f) cnt = 1.0f;
    float inv = 1.0f / cnt;
    s.x *= inv; s.y *= inv; s.z *= inv; s.w *= inv;
    *(float4*)&pooled[g*HD + lane*4] = s;
  }
}

// ---------------- classifier + log_softmax ----------------
__global__ __launch_bounds__(64) void classifier_kernel(
    const float* __restrict__ pooled,
    const float* __restrict__ gw, const float* __restrict__ gb,
    float* __restrict__ out)
{
  int g = blockIdx.x;
  int lane = threadIdx.x;
  float p0 = pooled[g*HD + lane];
  float p1 = pooled[g*HD + 64 + lane];
  float vals[NC];
  #pragma unroll
  for (int c=0;c<NC;c++){
    float s = p0*gw[c*HD + lane] + p1*gw[c*HD + 64 + lane];
    #pragma unroll
    for (int off=32; off>0; off>>=1) s += __shfl_down(s, off, 64);
    vals[c] = s;
  }
  if (lane == 0){
    float mx = -1e30f;
    #pragma unroll
    for (int c=0;c<NC;c++){ vals[c] += gb[c]; mx = fmaxf(mx, vals[c]); }
    float se = 0.f;
    #pragma unroll
    for (int c=0;c<NC;c++) se += __expf(vals[c] - mx);
    float lse = mx + __logf(se);
    #pragma unroll
    for (int c=0;c<NC;c++) out[g*NC + c] = vals[c] - lse;
  }
}

extern "C" void kernel_launch(void* const* d_in, const int* in_sizes, int n_in,
                              void* d_out, int out_size, void* d_ws, size_t ws_size,
                              hipStream_t stream)
{
  const float* x        = (const float*)d_in[0];
  const int*   ei       = (const int*)  d_in[1];
  const int*   batch    = (const int*)  d_in[2];
  const float* W        = (const float*)d_in[3];
  const float* w_ih     = (const float*)d_in[4];
  const float* w_hh     = (const float*)d_in[5];
  const float* b_ih     = (const float*)d_in[6];
  const float* b_hh     = (const float*)d_in[7];
  const float* local_w  = (const float*)d_in[8];
  const float* local_b  = (const float*)d_in[9];
  const float* global_w = (const float*)d_in[10];
  const float* global_b = (const float*)d_in[11];
  float* out = (float*)d_out;

  // workspace layout
  char* base = (char*)d_ws;
  char*   R       = base + 25600000;                  // 25.6 MB multi-use region
  ushort* sumh_bf = (ushort*)R;                       //   12.8 MB (live during layers)
  ushort* veffT   = (ushort*)(R + 12800000);          //   384 KB  (live during layers)
  ushort* whh_bf  = (ushort*)(R + 13193216);          //   96 KB   (live during layers)
  float*  bsums   = (float*)(R + 13291520);           //   2 KB    (live during layers)
  float*  local   = (float*)R;                        //   25.6 MB (after layers; clobbers the above)
  ushort* xbf     = (ushort*)(base + 51200000);       // 12.8 MB
  ushort* hbf     = (ushort*)(base + 64000000);       // 12.8 MB
  ushort* lw_bf   = (ushort*)(base + 76800000);       // 32 KB
  float*  pooled  = (float*)(base + 76832768);        // 128 KB
  int* row_ptr    = (int*)(base + 76963840);          // NN+1
  int* cursor     = row_ptr + (NN + 1);               // NN
  int* csr_src    = cursor + NN;                      // NE
  int* gptr       = csr_src + NE;                     // NG+1
  int* bsum       = gptr + (NG + 1);                  // 49

  const int* esrc = ei;
  const int* edst = ei + NE;

  hipMemsetAsync(cursor, 0, NN*sizeof(int), stream);
  prep_weights_bf16<<<259, 256, 0, stream>>>(w_hh, local_w, b_ih, b_hh, whh_bf, lw_bf, bsums);
  veff_kernel<<<768, 256, 0, stream>>>(W, w_ih, veffT);
  convert_x<<<6250, 256, 0, stream>>>((const float4*)x, (ushort4*)xbf);
  count_deg<<<3125, 256, 0, stream>>>(edst, cursor);
  scan_blocks<<<49, 1024, 0, stream>>>(cursor, row_ptr, bsum);
  scan_carry<<<1, 64, 0, stream>>>(bsum, row_ptr);
  scan_add<<<49, 1024, 0, stream>>>(bsum, row_ptr, cursor);
  fill_csr<<<3125, 256, 0, stream>>>(esrc, edst, cursor, csr_src);
  graph_ptr_kernel<<<5, 64, 0, stream>>>(batch, gptr);

  const ushort* hin_b = xbf;
  for (int l = 0; l < NL; l++){
    aggregate_bf16<<<12500, 256, 0, stream>>>((const uint*)hin_b, row_ptr, csr_src, (uint*)sumh_bf);
    // layer 0: read xbf, write hbf; layers 1+: in-place on hbf (blocks touch only own rows)
    gru_mfma4<<<782, 256, 0, stream>>>(sumh_bf, hbf, hin_b,
                                       veffT + (size_t)l*49152, whh_bf, bsums);
    hin_b = hbf;
  }

  local_gemm_mfma<<<782, 256, 0, stream>>>(hbf, lw_bf, local_b, local);
  pool_kernel<<<NG, 256, 0, stream>>>(local, gptr, pooled);
  classifier_kernel<<<NG, 64, 0, stream>>>(pooled, global_w, global_b, out);
}